// Round 2
// baseline (2087.141 us; speedup 1.0000x reference)
//
#include <hip/hip_runtime.h>

#define B_ 8
#define N_ 8192
#define D_ 256
#define H_ 8
#define NSPLIT 8
#define BN 65536  // B_*N_

typedef float f32x4 __attribute__((ext_vector_type(4)));
typedef __bf16 bf16x8 __attribute__((ext_vector_type(8)));

__device__ __forceinline__ unsigned short f2b(float f) {
  union { float f; unsigned u; } v; v.f = f;
  return (unsigned short)((v.u + 0x7fffu + ((v.u >> 16) & 1u)) >> 16);
}
__device__ __forceinline__ float b2f(unsigned short u) {
  union { unsigned u; float f; } v; v.u = ((unsigned)u) << 16;
  return v.f;
}

// ---------------------------------------------------------------------------
// Stage a 128x32 A-tile into swizzled LDS (bf16). ABF: source is bf16.
// ---------------------------------------------------------------------------
template <int ABF>
__device__ __forceinline__ void stageA(unsigned short* As, const void* Av, int la,
                                       int rowBase, int ka, int t) {
  if (ABF) {
    const unsigned short* Ap = (const unsigned short*)Av;
#pragma unroll
    for (int i = 0; i < 2; ++i) {
      int slot = t + 256 * i;          // 512 slots: 128 rows x 4 k-octets
      int row = slot >> 2, ko = slot & 3;
      uint4 v = *reinterpret_cast<const uint4*>(&Ap[(size_t)(rowBase + row) * la + ka + ko * 8]);
      int cw = (row + (row >> 2)) & 3;
      *reinterpret_cast<uint4*>(&As[row * 32 + ((ko ^ cw) << 3)]) = v;
    }
  } else {
    const float* Ap = (const float*)Av;
#pragma unroll
    for (int i = 0; i < 4; ++i) {
      int slot = t + 256 * i;          // 1024 slots: 128 rows x 8 k-quads
      int row = slot >> 3, kq = slot & 7;
      float4 v = *reinterpret_cast<const float4*>(&Ap[(size_t)(rowBase + row) * la + ka + kq * 4]);
      ushort4 p; p.x = f2b(v.x); p.y = f2b(v.y); p.z = f2b(v.z); p.w = f2b(v.w);
      int cw = (row + (row >> 2)) & 3;
      int off = (((kq >> 1) ^ cw) << 3) | ((kq & 1) << 2);
      *reinterpret_cast<ushort4*>(&As[row * 32 + off]) = p;
    }
  }
}

// ---------------------------------------------------------------------------
// bf16-MFMA GEMM: C[M x Nc] = act( A[M x K] @ B[K x Nc] )
// A split at k=256 between (A1,lda1) and (A2,lda2); B split at k=256 (B1,B2).
// MODE 0: C = acc + bias(optional)
// MODE 1: C = relu(acc + bias)
// MODE 2: C = sigmoid(acc - bias)                       (z-gate; bias = bg)
// MODE 3: C = sigmoid(acc) * auxX[row,col]              (r * x fused)
// MODE 4: C = (1-z)*auxX + z*tanh(acc), z=bf16 auxZ     (full gate combine)
// ---------------------------------------------------------------------------
template <int MODE, int A1BF, int A2BF, int CBF>
__global__ __launch_bounds__(256) void gemm_kernel(
    const void* __restrict__ A1v, int lda1, const void* __restrict__ A2v, int lda2,
    const float* __restrict__ B1, const float* __restrict__ B2, int ldb,
    const float* __restrict__ bias, const float* __restrict__ auxX,
    const unsigned short* __restrict__ auxZ,
    void* __restrict__ Cv, int ldc, int K) {
  __shared__ __align__(16) unsigned short As[128 * 32];
  __shared__ __align__(16) unsigned short Bs[128 * 32];
  const int t = threadIdx.x;
  const int rowBase = blockIdx.y * 128;
  const int colBase = blockIdx.x * 128;
  const int lane = t & 63;
  const int w = t >> 6;
  const int wrow = (w >> 1) * 64, wcol = (w & 1) * 64;
  const int lr = lane & 15;
  const int kg = lane >> 4;
  const int cL = (lr + (lr >> 2)) & 3;
  const int swz = (kg ^ cL) << 3;

  f32x4 acc[4][4];
#pragma unroll
  for (int m = 0; m < 4; ++m)
#pragma unroll
    for (int n = 0; n < 4; ++n) acc[m][n] = 0.f;

  for (int k0 = 0; k0 < K; k0 += 32) {
    if (k0) __syncthreads();
    if (k0 < 256) stageA<A1BF>(As, A1v, lda1, rowBase, k0, t);
    else          stageA<A2BF>(As, A2v, lda2, rowBase, k0 - 256, t);
    {
      const float* Bp = (k0 < 256) ? B1 : B2;
      int kb = (k0 < 256) ? k0 : k0 - 256;
#pragma unroll
      for (int i = 0; i < 4; ++i) {
        int slot = t + 256 * i;
        int col = slot & 127, kq = slot >> 7;
        float b0 = Bp[(size_t)(kb + kq * 4 + 0) * ldb + colBase + col];
        float b1 = Bp[(size_t)(kb + kq * 4 + 1) * ldb + colBase + col];
        float b2 = Bp[(size_t)(kb + kq * 4 + 2) * ldb + colBase + col];
        float b3 = Bp[(size_t)(kb + kq * 4 + 3) * ldb + colBase + col];
        ushort4 p; p.x = f2b(b0); p.y = f2b(b1); p.z = f2b(b2); p.w = f2b(b3);
        int cw = (col + (col >> 2)) & 3;
        int off = (((kq >> 1) ^ cw) << 3) | ((kq & 1) << 2);
        *reinterpret_cast<ushort4*>(&Bs[col * 32 + off]) = p;
      }
    }
    __syncthreads();
    bf16x8 af[4], bfr[4];
#pragma unroll
    for (int m = 0; m < 4; ++m)
      af[m] = *reinterpret_cast<const bf16x8*>(&As[(wrow + m * 16 + lr) * 32 + swz]);
#pragma unroll
    for (int n = 0; n < 4; ++n)
      bfr[n] = *reinterpret_cast<const bf16x8*>(&Bs[(wcol + n * 16 + lr) * 32 + swz]);
#pragma unroll
    for (int m = 0; m < 4; ++m)
#pragma unroll
      for (int n = 0; n < 4; ++n)
        acc[m][n] = __builtin_amdgcn_mfma_f32_16x16x32_bf16(af[m], bfr[n], acc[m][n], 0, 0, 0);
  }
  // epilogue: row = wrow+m*16+kg*4+i, col = wcol+n*16+lr  (m89-verified C layout)
#pragma unroll
  for (int n = 0; n < 4; ++n) {
    int col = colBase + wcol + n * 16 + lr;
    float bv = 0.f;
    if (MODE == 0 || MODE == 1) { if (bias) bv = bias[col]; }
    if (MODE == 2) bv = bias[col];
#pragma unroll
    for (int m = 0; m < 4; ++m) {
#pragma unroll
      for (int i = 0; i < 4; ++i) {
        int row = rowBase + wrow + m * 16 + kg * 4 + i;
        float v = acc[m][n][i];
        float o;
        if (MODE == 0) o = v + bv;
        else if (MODE == 1) o = fmaxf(v + bv, 0.f);
        else if (MODE == 2) o = 1.f / (1.f + __expf(-(v - bv)));
        else if (MODE == 3) o = (1.f / (1.f + __expf(-v))) * auxX[(size_t)row * 256 + col];
        else {
          float z = b2f(auxZ[(size_t)row * 256 + col]);
          float xv = auxX[(size_t)row * 256 + col];
          o = (1.f - z) * xv + z * tanhf(v);
        }
        if (CBF) ((unsigned short*)Cv)[(size_t)row * ldc + col] = f2b(o);
        else     ((float*)Cv)[(size_t)row * ldc + col] = o;
      }
    }
  }
}

// ---------------------------------------------------------------------------
// LayerNorm over last dim (256). One wave per row, float4 per lane.
// ---------------------------------------------------------------------------
__global__ __launch_bounds__(256) void ln_kernel(const float* __restrict__ x,
                                                 const float* __restrict__ g,
                                                 const float* __restrict__ b,
                                                 float* __restrict__ out) {
  const int row = blockIdx.x * 4 + (threadIdx.x >> 6);
  const int lane = threadIdx.x & 63;
  const float4 v = *reinterpret_cast<const float4*>(&x[(size_t)row * 256 + lane * 4]);
  float s = v.x + v.y + v.z + v.w;
  float s2 = v.x * v.x + v.y * v.y + v.z * v.z + v.w * v.w;
#pragma unroll
  for (int off = 1; off < 64; off <<= 1) {
    s += __shfl_xor(s, off);
    s2 += __shfl_xor(s2, off);
  }
  const float mu = s * (1.f / 256.f);
  const float var = s2 * (1.f / 256.f) - mu * mu;
  const float rs = rsqrtf(var + 1e-3f);
  const float4 gv = *reinterpret_cast<const float4*>(&g[lane * 4]);
  const float4 bv = *reinterpret_cast<const float4*>(&b[lane * 4]);
  float4 o;
  o.x = gv.x * (v.x - mu) * rs + bv.x;
  o.y = gv.y * (v.y - mu) * rs + bv.y;
  o.z = gv.z * (v.z - mu) * rs + bv.z;
  o.w = gv.w * (v.w - mu) * rs + bv.w;
  *reinterpret_cast<float4*>(&out[(size_t)row * 256 + lane * 4]) = o;
}

// ---------------------------------------------------------------------------
// Performer phase A: per (b,h,split) partial kv[64x32] and s[64] over 1024 toks
// part layout: [bh][split][ m*32+d (2048) | s (64) ]  (stride 2112)
// ---------------------------------------------------------------------------
__global__ __launch_bounds__(256) void kv_partial_kernel(const float* __restrict__ Kb,
                                                         const float* __restrict__ Vb,
                                                         const float* __restrict__ omega,
                                                         float* __restrict__ part) {
  __shared__ float om[2048];      // [d*64+m]
  __shared__ float kk[64 * 33];
  __shared__ float vv[64 * 33];
  __shared__ float pk[64 * 65];
  __shared__ float sqv[64];
  const int bh = blockIdx.x, split = blockIdx.y;
  const int b = bh >> 3, h = bh & 7;
  const int t = threadIdx.x;
  for (int i = t; i < 2048; i += 256) om[i] = omega[i];
  float acc[8], sacc[8];
#pragma unroll
  for (int j = 0; j < 8; ++j) { acc[j] = 0.f; sacc[j] = 0.f; }
  const int d = t & 31, mg = t >> 5;
  const float scale = 0.4204482076268573f;  // 32^-0.25
  const size_t rbase = (size_t)b * N_ + (size_t)split * (N_ / NSPLIT);
  for (int tile = 0; tile < (N_ / NSPLIT) / 64; ++tile) {
    __syncthreads();
#pragma unroll
    for (int i = 0; i < 8; ++i) {
      int idx = t + 256 * i;
      int tok = idx >> 5, dd = idx & 31;
      size_t gro = (rbase + tile * 64 + tok) * 256 + h * 32 + dd;
      kk[tok * 33 + dd] = Kb[gro] * scale;
      vv[tok * 33 + dd] = Vb[gro];
    }
    __syncthreads();
    if (t < 64) {
      float sx = 0.f;
#pragma unroll
      for (int dd = 0; dd < 32; ++dd) { float q = kk[t * 33 + dd]; sx += q * q; }
      sqv[t] = 0.5f * sx;
    }
    __syncthreads();
#pragma unroll
    for (int i = 0; i < 16; ++i) {
      int idx = t + 256 * i;
      int tok = idx >> 6, m = idx & 63;
      float dot = 0.f;
#pragma unroll
      for (int dd = 0; dd < 32; ++dd) dot = __fmaf_rn(kk[tok * 33 + dd], om[dd * 64 + m], dot);
      pk[tok * 65 + m] = __expf(dot - sqv[tok]) * 0.125f;
    }
    __syncthreads();
    for (int tok = 0; tok < 64; ++tok) {
      float vval = vv[tok * 33 + d];
#pragma unroll
      for (int mm = 0; mm < 8; ++mm) {
        float p = pk[tok * 65 + mg * 8 + mm];
        acc[mm] = __fmaf_rn(p, vval, acc[mm]);
        sacc[mm] += p;
      }
    }
  }
  float* dst = part + (size_t)(bh * NSPLIT + split) * 2112;
#pragma unroll
  for (int mm = 0; mm < 8; ++mm) dst[(mg * 8 + mm) * 32 + d] = acc[mm];
  if (d == 0) {
#pragma unroll
    for (int mm = 0; mm < 8; ++mm) dst[2048 + mg * 8 + mm] = sacc[mm];
  }
}

__global__ __launch_bounds__(256) void kv_reduce_kernel(const float* __restrict__ part,
                                                        float* __restrict__ fin) {
  const int bh = blockIdx.x, t = threadIdx.x;
  for (int idx = t; idx < 2112; idx += 256) {
    float s = 0.f;
#pragma unroll
    for (int sp = 0; sp < NSPLIT; ++sp) s += part[(size_t)(bh * NSPLIT + sp) * 2112 + idx];
    fin[(size_t)bh * 2112 + idx] = s;
  }
}

// ---------------------------------------------------------------------------
// Performer phase B: att[b,n,h*32+d] = (phi_q @ kv) / (phi_q @ s)
// ---------------------------------------------------------------------------
__global__ __launch_bounds__(256) void attn_num_kernel(const float* __restrict__ Qb,
                                                       const float* __restrict__ fin,
                                                       const float* __restrict__ omega,
                                                       float* __restrict__ att) {
  __shared__ float om[2048];
  __shared__ float qq[64 * 33];
  __shared__ float pq[64 * 65];
  __shared__ float kvL[64 * 33];
  __shared__ float sL[64];
  __shared__ float sqv[64];
  __shared__ float den[64];
  const int bh = blockIdx.x;
  const int b = bh >> 3, h = bh & 7;
  const int t = threadIdx.x;
  for (int i = t; i < 2048; i += 256) {
    om[i] = omega[i];
    int m = i >> 5, dd = i & 31;
    kvL[m * 33 + dd] = fin[(size_t)bh * 2112 + m * 32 + dd];
  }
  if (t < 64) sL[t] = fin[(size_t)bh * 2112 + 2048 + t];
  const float scale = 0.4204482076268573f;
  const size_t row0 = (size_t)b * N_ + (size_t)blockIdx.y * 64;
#pragma unroll
  for (int i = 0; i < 8; ++i) {
    int idx = t + 256 * i;
    int tok = idx >> 5, dd = idx & 31;
    qq[tok * 33 + dd] = Qb[(row0 + tok) * 256 + h * 32 + dd] * scale;
  }
  __syncthreads();
  if (t < 64) {
    float sx = 0.f;
#pragma unroll
    for (int dd = 0; dd < 32; ++dd) { float q = qq[t * 33 + dd]; sx += q * q; }
    sqv[t] = 0.5f * sx;
  }
  __syncthreads();
#pragma unroll
  for (int i = 0; i < 16; ++i) {
    int idx = t + 256 * i;
    int tok = idx >> 6, m = idx & 63;
    float dot = 0.f;
#pragma unroll
    for (int dd = 0; dd < 32; ++dd) dot = __fmaf_rn(qq[tok * 33 + dd], om[dd * 64 + m], dot);
    pq[tok * 65 + m] = __expf(dot - sqv[tok]) * 0.125f;
  }
  __syncthreads();
  if (t < 64) {
    float dn = 0.f;
#pragma unroll
    for (int m = 0; m < 64; ++m) dn = __fmaf_rn(pq[t * 65 + m], sL[m], dn);
    den[t] = dn;
  }
  __syncthreads();
  const int d = t & 31, tg = t >> 5;
#pragma unroll
  for (int j = 0; j < 8; ++j) {
    int tok = tg * 8 + j;
    float num = 0.f;
#pragma unroll
    for (int m = 0; m < 64; ++m) num = __fmaf_rn(pq[tok * 65 + m], kvL[m * 33 + d], num);
    att[(row0 + tok) * 256 + h * 32 + d] = num / den[tok];
  }
}

extern "C" void kernel_launch(void* const* d_in, const int* in_sizes, int n_in,
                              void* d_out, int out_size, void* d_ws, size_t ws_size,
                              hipStream_t stream) {
  (void)in_sizes; (void)n_in; (void)out_size; (void)ws_size;
  const float* x     = (const float*)d_in[0];
  const float* ln1_g = (const float*)d_in[1];
  const float* ln1_b = (const float*)d_in[2];
  const float* Wq    = (const float*)d_in[3];
  const float* bq    = (const float*)d_in[4];
  const float* Wk    = (const float*)d_in[5];
  const float* bk    = (const float*)d_in[6];
  const float* Wv    = (const float*)d_in[7];
  const float* bv    = (const float*)d_in[8];
  const float* Wo    = (const float*)d_in[9];
  const float* bo    = (const float*)d_in[10];
  const float* omega = (const float*)d_in[11];
  const float* g1_Wr = (const float*)d_in[12];
  const float* g1_Ur = (const float*)d_in[13];
  const float* g1_Wz = (const float*)d_in[14];
  const float* g1_Uz = (const float*)d_in[15];
  const float* g1_Wg = (const float*)d_in[16];
  const float* g1_Ug = (const float*)d_in[17];
  const float* g1_bg = (const float*)d_in[18];
  const float* ln2_g = (const float*)d_in[19];
  const float* ln2_b = (const float*)d_in[20];
  const float* W1    = (const float*)d_in[21];
  const float* b1    = (const float*)d_in[22];
  const float* W2    = (const float*)d_in[23];
  const float* b2    = (const float*)d_in[24];
  const float* g2_Wr = (const float*)d_in[25];
  const float* g2_Ur = (const float*)d_in[26];
  const float* g2_Wz = (const float*)d_in[27];
  const float* g2_Uz = (const float*)d_in[28];
  const float* g2_Wg = (const float*)d_in[29];
  const float* g2_Ug = (const float*)d_in[30];
  const float* g2_bg = (const float*)d_in[31];

  const size_t SZ  = (size_t)BN * 256;   // 16.78M elements
  float* T1 = (float*)d_ws;              // 67 MB
  float* T2 = T1 + SZ;                   // 67 MB
  float* kvpart = T2 + SZ;               // 64*8*2112 floats (4.3 MB)
  float* kvfin  = kvpart + 64 * NSPLIT * 2112;  // 0.54 MB
  float* dof = (float*)d_out;            // d_out used as scratch (67 MB)
  unsigned short* db = (unsigned short*)d_out;  // bf16 view
  const size_t HSZ = SZ;                 // ushort offset for second bf16 half

  dim3 blk(256);
  dim3 g256(2, BN / 128);
  dim3 g512(4, BN / 128);

  // ---- attention half ----
  ln_kernel<<<BN / 4, blk, 0, stream>>>(x, ln1_g, ln1_b, T1);                       // T1 = h
  gemm_kernel<0,0,0,0><<<g256, blk, 0, stream>>>(T1,256, nullptr,0, Wk,nullptr,256, bk, nullptr,nullptr, T2,256, 256);   // T2 = k
  gemm_kernel<0,0,0,0><<<g256, blk, 0, stream>>>(T1,256, nullptr,0, Wv,nullptr,256, bv, nullptr,nullptr, dof,256, 256);  // dout = v
  kv_partial_kernel<<<dim3(64, NSPLIT), blk, 0, stream>>>(T2, dof, omega, kvpart);
  kv_reduce_kernel<<<64, blk, 0, stream>>>(kvpart, kvfin);
  gemm_kernel<0,0,0,0><<<g256, blk, 0, stream>>>(T1,256, nullptr,0, Wq,nullptr,256, bq, nullptr,nullptr, T2,256, 256);   // T2 = q
  attn_num_kernel<<<dim3(64, N_ / 64), blk, 0, stream>>>(T2, kvfin, omega, T1);     // T1 = att
  gemm_kernel<0,0,0,0><<<g256, blk, 0, stream>>>(T1,256, nullptr,0, Wo,nullptr,256, bo, nullptr,nullptr, T2,256, 256);   // T2 = y1
  // ---- gate 1 (y=T2, x=input) ----
  gemm_kernel<3,0,0,1><<<g256, blk, 0, stream>>>(T2,256, x,256, g1_Wr,g1_Ur,256, nullptr, x, nullptr, db,256, 512);      // rx1 (bf16, dout lo)
  gemm_kernel<2,0,0,1><<<g256, blk, 0, stream>>>(T2,256, x,256, g1_Wz,g1_Uz,256, g1_bg, nullptr,nullptr, db+HSZ,256, 512); // z1 (bf16, dout hi)
  gemm_kernel<4,0,1,0><<<g256, blk, 0, stream>>>(T2,256, db,256, g1_Wg,g1_Ug,256, nullptr, x, db+HSZ, T1,256, 512);      // T1 = out1
  // ---- MLP ----
  ln_kernel<<<BN / 4, blk, 0, stream>>>(T1, ln2_g, ln2_b, T2);                      // T2 = ln2
  gemm_kernel<1,0,0,1><<<g512, blk, 0, stream>>>(T2,256, nullptr,0, W1,nullptr,512, b1, nullptr,nullptr, db,512, 256);   // dout = hid (bf16 [M][512])
  gemm_kernel<0,1,1,0><<<g256, blk, 0, stream>>>(db,512, db+256,512, W2, W2+(size_t)256*256,256, b2, nullptr,nullptr, T2,256, 512); // T2 = y2
  // ---- gate 2 (y=T2, x=out1=T1) ----
  gemm_kernel<3,0,0,1><<<g256, blk, 0, stream>>>(T2,256, T1,256, g2_Wr,g2_Ur,256, nullptr, T1, nullptr, db,256, 512);    // rx2 (bf16)
  gemm_kernel<2,0,0,1><<<g256, blk, 0, stream>>>(T2,256, T1,256, g2_Wz,g2_Uz,256, g2_bg, nullptr,nullptr, db+HSZ,256, 512); // z2 (bf16)
  gemm_kernel<4,0,1,0><<<g256, blk, 0, stream>>>(T2,256, db,256, g2_Wg,g2_Ug,256, nullptr, T1, db+HSZ, T1,256, 512);     // T1 = final out
  hipMemcpyAsync(d_out, T1, SZ * sizeof(float), hipMemcpyDeviceToDevice, stream);
}

// Round 3
// 1305.861 us; speedup vs baseline: 1.5983x; 1.5983x over previous
//
#include <hip/hip_runtime.h>

#define B_ 8
#define N_ 8192
#define D_ 256
#define H_ 8
#define KSPLIT 16
#define BN 65536  // B_*N_

typedef float f32x4 __attribute__((ext_vector_type(4)));
typedef __bf16 bf16x8 __attribute__((ext_vector_type(8)));

__device__ __forceinline__ unsigned short f2b(float f) {
  union { float f; unsigned u; } v; v.f = f;
  return (unsigned short)((v.u + 0x7fffu + ((v.u >> 16) & 1u)) >> 16);
}
__device__ __forceinline__ float b2f(unsigned short u) {
  union { unsigned u; float f; } v; v.u = ((unsigned)u) << 16;
  return v.f;
}

// ---------------------------------------------------------------------------
// Stage a 128x32 A-tile into swizzled LDS (bf16). ABF: source is bf16.
// ---------------------------------------------------------------------------
template <int ABF>
__device__ __forceinline__ void stageA(unsigned short* As, const void* Av, int la,
                                       int rowBase, int ka, int t) {
  if (ABF) {
    const unsigned short* Ap = (const unsigned short*)Av;
#pragma unroll
    for (int i = 0; i < 2; ++i) {
      int slot = t + 256 * i;          // 512 slots: 128 rows x 4 k-octets
      int row = slot >> 2, ko = slot & 3;
      uint4 v = *reinterpret_cast<const uint4*>(&Ap[(size_t)(rowBase + row) * la + ka + ko * 8]);
      int cw = (row + (row >> 2)) & 3;
      *reinterpret_cast<uint4*>(&As[row * 32 + ((ko ^ cw) << 3)]) = v;
    }
  } else {
    const float* Ap = (const float*)Av;
#pragma unroll
    for (int i = 0; i < 4; ++i) {
      int slot = t + 256 * i;          // 1024 slots: 128 rows x 8 k-quads
      int row = slot >> 3, kq = slot & 7;
      float4 v = *reinterpret_cast<const float4*>(&Ap[(size_t)(rowBase + row) * la + ka + kq * 4]);
      ushort4 p; p.x = f2b(v.x); p.y = f2b(v.y); p.z = f2b(v.z); p.w = f2b(v.w);
      int cw = (row + (row >> 2)) & 3;
      int off = (((kq >> 1) ^ cw) << 3) | ((kq & 1) << 2);
      *reinterpret_cast<ushort4*>(&As[row * 32 + off]) = p;
    }
  }
}

// ---------------------------------------------------------------------------
// bf16-MFMA GEMM: C[M x Nc] = act( A[M x K] @ B[K x Nc] )
// MODE 0: C = acc + bias(optional)
// MODE 1: C = relu(acc + bias)
// MODE 2: C = sigmoid(acc - bias)
// MODE 3: C = sigmoid(acc) * auxX[row,col]
// MODE 4: C = (1-z)*auxX + z*tanh(acc), z=bf16 auxZ
// MODE 5: C = exp(acc - auxX[row*8 + col/64]) * 0.125   (phi epilogue)
// MODE 6: C = acc * auxX[row*8 + col/32]                (num * 1/den)
// BSEL: B pointer += (blockIdx.y>>6)*131072 (per-batch kv blockdiag)
// ---------------------------------------------------------------------------
template <int MODE, int A1BF, int A2BF, int CBF, int BSEL>
__global__ __launch_bounds__(256) void gemm_kernel(
    const void* __restrict__ A1v, int lda1, const void* __restrict__ A2v, int lda2,
    const float* __restrict__ B1, const float* __restrict__ B2, int ldb,
    const float* __restrict__ bias, const float* __restrict__ auxX,
    const unsigned short* __restrict__ auxZ,
    void* __restrict__ Cv, int ldc, int K) {
  __shared__ __align__(16) unsigned short As[128 * 32];
  __shared__ __align__(16) unsigned short Bs[128 * 32];
  const int t = threadIdx.x;
  const int rowBase = blockIdx.y * 128;
  const int colBase = blockIdx.x * 128;
  if (BSEL) {
    size_t boff = (size_t)(blockIdx.y >> 6) * 131072;
    B1 += boff; B2 += boff;
  }
  const int lane = t & 63;
  const int w = t >> 6;
  const int wrow = (w >> 1) * 64, wcol = (w & 1) * 64;
  const int lr = lane & 15;
  const int kg = lane >> 4;
  const int cL = (lr + (lr >> 2)) & 3;
  const int swz = (kg ^ cL) << 3;

  f32x4 acc[4][4];
#pragma unroll
  for (int m = 0; m < 4; ++m)
#pragma unroll
    for (int n = 0; n < 4; ++n) acc[m][n] = 0.f;

  for (int k0 = 0; k0 < K; k0 += 32) {
    if (k0) __syncthreads();
    if (k0 < 256) stageA<A1BF>(As, A1v, lda1, rowBase, k0, t);
    else          stageA<A2BF>(As, A2v, lda2, rowBase, k0 - 256, t);
    {
      const float* Bp = (k0 < 256) ? B1 : B2;
      int kb = (k0 < 256) ? k0 : k0 - 256;
#pragma unroll
      for (int i = 0; i < 4; ++i) {
        int slot = t + 256 * i;
        int col = slot & 127, kq = slot >> 7;
        float b0 = Bp[(size_t)(kb + kq * 4 + 0) * ldb + colBase + col];
        float b1 = Bp[(size_t)(kb + kq * 4 + 1) * ldb + colBase + col];
        float b2 = Bp[(size_t)(kb + kq * 4 + 2) * ldb + colBase + col];
        float b3 = Bp[(size_t)(kb + kq * 4 + 3) * ldb + colBase + col];
        ushort4 p; p.x = f2b(b0); p.y = f2b(b1); p.z = f2b(b2); p.w = f2b(b3);
        int cw = (col + (col >> 2)) & 3;
        int off = (((kq >> 1) ^ cw) << 3) | ((kq & 1) << 2);
        *reinterpret_cast<ushort4*>(&Bs[col * 32 + off]) = p;
      }
    }
    __syncthreads();
    bf16x8 af[4], bfr[4];
#pragma unroll
    for (int m = 0; m < 4; ++m)
      af[m] = *reinterpret_cast<const bf16x8*>(&As[(wrow + m * 16 + lr) * 32 + swz]);
#pragma unroll
    for (int n = 0; n < 4; ++n)
      bfr[n] = *reinterpret_cast<const bf16x8*>(&Bs[(wcol + n * 16 + lr) * 32 + swz]);
#pragma unroll
    for (int m = 0; m < 4; ++m)
#pragma unroll
      for (int n = 0; n < 4; ++n)
        acc[m][n] = __builtin_amdgcn_mfma_f32_16x16x32_bf16(af[m], bfr[n], acc[m][n], 0, 0, 0);
  }
  // epilogue: row = wrow+m*16+kg*4+i, col = wcol+n*16+lr
#pragma unroll
  for (int n = 0; n < 4; ++n) {
    int col = colBase + wcol + n * 16 + lr;
    float bv = 0.f;
    if (MODE == 0 || MODE == 1) { if (bias) bv = bias[col]; }
    if (MODE == 2) bv = bias[col];
#pragma unroll
    for (int m = 0; m < 4; ++m) {
#pragma unroll
      for (int i = 0; i < 4; ++i) {
        int row = rowBase + wrow + m * 16 + kg * 4 + i;
        float v = acc[m][n][i];
        float o;
        if (MODE == 0) o = v + bv;
        else if (MODE == 1) o = fmaxf(v + bv, 0.f);
        else if (MODE == 2) o = 1.f / (1.f + __expf(-(v - bv)));
        else if (MODE == 3) o = (1.f / (1.f + __expf(-v))) * auxX[(size_t)row * 256 + col];
        else if (MODE == 4) {
          float z = b2f(auxZ[(size_t)row * 256 + col]);
          float xv = auxX[(size_t)row * 256 + col];
          o = (1.f - z) * xv + z * tanhf(v);
        } else if (MODE == 5) {
          o = __expf(v - auxX[(size_t)row * 8 + (col >> 6)]) * 0.125f;
        } else {  // MODE 6
          o = v * auxX[(size_t)row * 8 + (col >> 5)];
        }
        if (CBF) ((unsigned short*)Cv)[(size_t)row * ldc + col] = f2b(o);
        else     ((float*)Cv)[(size_t)row * ldc + col] = o;
      }
    }
  }
}

// ---------------------------------------------------------------------------
__global__ __launch_bounds__(256) void ln_kernel(const float* __restrict__ x,
                                                 const float* __restrict__ g,
                                                 const float* __restrict__ b,
                                                 float* __restrict__ out) {
  const int row = blockIdx.x * 4 + (threadIdx.x >> 6);
  const int lane = threadIdx.x & 63;
  const float4 v = *reinterpret_cast<const float4*>(&x[(size_t)row * 256 + lane * 4]);
  float s = v.x + v.y + v.z + v.w;
  float s2 = v.x * v.x + v.y * v.y + v.z * v.z + v.w * v.w;
#pragma unroll
  for (int off = 1; off < 64; off <<= 1) {
    s += __shfl_xor(s, off);
    s2 += __shfl_xor(s2, off);
  }
  const float mu = s * (1.f / 256.f);
  const float var = s2 * (1.f / 256.f) - mu * mu;
  const float rs = rsqrtf(var + 1e-3f);
  const float4 gv = *reinterpret_cast<const float4*>(&g[lane * 4]);
  const float4 bv = *reinterpret_cast<const float4*>(&b[lane * 4]);
  float4 o;
  o.x = gv.x * (v.x - mu) * rs + bv.x;
  o.y = gv.y * (v.y - mu) * rs + bv.y;
  o.z = gv.z * (v.z - mu) * rs + bv.z;
  o.w = gv.w * (v.w - mu) * rs + bv.w;
  *reinterpret_cast<float4*>(&out[(size_t)row * 256 + lane * 4]) = o;
}

// per-head 0.5*scale^2*sum(x^2): sq[row*8+h]
__global__ __launch_bounds__(256) void sqh_kernel(const float* __restrict__ X,
                                                  float* __restrict__ sq, float coef) {
  const int row = blockIdx.x * 4 + (threadIdx.x >> 6);
  const int lane = threadIdx.x & 63;
  const float4 v = *reinterpret_cast<const float4*>(&X[(size_t)row * 256 + lane * 4]);
  float s = v.x * v.x + v.y * v.y + v.z * v.z + v.w * v.w;
  s += __shfl_xor(s, 1);
  s += __shfl_xor(s, 2);
  s += __shfl_xor(s, 4);
  if ((lane & 7) == 0) sq[(size_t)row * 8 + (lane >> 3)] = coef * s;
}

// W_phi[r=256][c=512] blockdiag: W_phi[d+32h][m+64h] = omega[d][m]*scale
__global__ __launch_bounds__(256) void wphi_kernel(const float* __restrict__ omega,
                                                   float* __restrict__ wphi) {
  int idx = blockIdx.x * 256 + threadIdx.x;
  int r = idx >> 9, c = idx & 511;
  float v = 0.f;
  if ((r >> 5) == (c >> 6)) v = omega[(r & 31) * 64 + (c & 63)] * 0.4204482076268573f;
  wphi[idx] = v;
}

// kvbd[b][r=512][c=256]: blockdiag of kvfin[bh][m*32+d]
__global__ __launch_bounds__(256) void kvbd_kernel(const float* __restrict__ kvfin,
                                                   float* __restrict__ kvbd) {
  int idx = blockIdx.x * 256 + threadIdx.x;
  int b = idx >> 17, rem = idx & 131071;
  int r = rem >> 8, c = rem & 255;
  float v = 0.f;
  if ((r >> 6) == (c >> 5))
    v = kvfin[(size_t)(b * 8 + (r >> 6)) * 2112 + (r & 63) * 32 + (c & 31)];
  kvbd[idx] = v;
}

// ---------------------------------------------------------------------------
// kv partial: per (bh, split) accumulate kv[64][32] + s[64] over N_/KSPLIT toks
// pk: bf16 [BN][512], v: bf16 [BN][256]
// ---------------------------------------------------------------------------
__global__ __launch_bounds__(256) void kv_partial2_kernel(const unsigned short* __restrict__ pk,
                                                          const unsigned short* __restrict__ v,
                                                          float* __restrict__ part) {
  __shared__ __align__(16) unsigned short pks[128 * 64];
  __shared__ __align__(16) unsigned short vs[128 * 32];
  const int bh = blockIdx.x, split = blockIdx.y;
  const int b = bh >> 3, h = bh & 7;
  const int t = threadIdx.x;
  const int d = t & 31, mg = t >> 5;
  float acc[8], sacc[8];
#pragma unroll
  for (int j = 0; j < 8; ++j) { acc[j] = 0.f; sacc[j] = 0.f; }
  const size_t rbase = (size_t)b * N_ + (size_t)split * (N_ / KSPLIT);
  for (int tile = 0; tile < (N_ / KSPLIT) / 128; ++tile) {
    __syncthreads();
#pragma unroll
    for (int i = 0; i < 4; ++i) {
      int slot = t + 256 * i;
      int tok = slot >> 3, mo = slot & 7;
      uint4 q = *reinterpret_cast<const uint4*>(&pk[(rbase + tile * 128 + tok) * 512 + h * 64 + mo * 8]);
      *reinterpret_cast<uint4*>(&pks[tok * 64 + mo * 8]) = q;
    }
#pragma unroll
    for (int i = 0; i < 2; ++i) {
      int slot = t + 256 * i;
      int tok = slot >> 2, qo = slot & 3;
      uint4 q = *reinterpret_cast<const uint4*>(&v[(rbase + tile * 128 + tok) * 256 + h * 32 + qo * 8]);
      *reinterpret_cast<uint4*>(&vs[tok * 32 + qo * 8]) = q;
    }
    __syncthreads();
#pragma unroll 2
    for (int tok = 0; tok < 128; ++tok) {
      float vval = b2f(vs[tok * 32 + d]);
      uint4 pv = *reinterpret_cast<const uint4*>(&pks[tok * 64 + mg * 8]);
      const unsigned uu[4] = {pv.x, pv.y, pv.z, pv.w};
#pragma unroll
      for (int j = 0; j < 4; ++j) {
        union { unsigned u; float f; } lo, hi;
        lo.u = uu[j] << 16; hi.u = uu[j] & 0xffff0000u;
        acc[2 * j]     = __fmaf_rn(lo.f, vval, acc[2 * j]);
        acc[2 * j + 1] = __fmaf_rn(hi.f, vval, acc[2 * j + 1]);
        sacc[2 * j] += lo.f; sacc[2 * j + 1] += hi.f;
      }
    }
  }
  float* dst = part + (size_t)(bh * KSPLIT + split) * 2112;
#pragma unroll
  for (int mm = 0; mm < 8; ++mm) dst[(mg * 8 + mm) * 32 + d] = acc[mm];
  if (d == 0) {
#pragma unroll
    for (int mm = 0; mm < 8; ++mm) dst[2048 + mg * 8 + mm] = sacc[mm];
  }
}

__global__ __launch_bounds__(256) void kv_reduce_kernel(const float* __restrict__ part,
                                                        float* __restrict__ fin) {
  const int bh = blockIdx.x, t = threadIdx.x;
  for (int idx = t; idx < 2112; idx += 256) {
    float s = 0.f;
#pragma unroll
    for (int sp = 0; sp < KSPLIT; ++sp) s += part[(size_t)(bh * KSPLIT + sp) * 2112 + idx];
    fin[(size_t)bh * 2112 + idx] = s;
  }
}

// rden[row*8+h] = 1 / sum_m pq[row,64h+m]*s[bh][m]
__global__ __launch_bounds__(256) void den_kernel(const unsigned short* __restrict__ pq,
                                                  const float* __restrict__ kvfin,
                                                  float* __restrict__ rden) {
  const int row = blockIdx.x * 4 + (threadIdx.x >> 6);
  const int lane = threadIdx.x & 63;
  const int h = lane >> 3, m0 = (lane & 7) * 8;
  const int b = row >> 13;
  const float* s = &kvfin[(size_t)(b * 8 + h) * 2112 + 2048 + m0];
  uint4 pv = *reinterpret_cast<const uint4*>(&pq[(size_t)row * 512 + h * 64 + m0]);
  const unsigned uu[4] = {pv.x, pv.y, pv.z, pv.w};
  float acc = 0.f;
#pragma unroll
  for (int j = 0; j < 4; ++j) {
    union { unsigned u; float f; } lo, hi;
    lo.u = uu[j] << 16; hi.u = uu[j] & 0xffff0000u;
    acc = __fmaf_rn(lo.f, s[2 * j], acc);
    acc = __fmaf_rn(hi.f, s[2 * j + 1], acc);
  }
  acc += __shfl_xor(acc, 1);
  acc += __shfl_xor(acc, 2);
  acc += __shfl_xor(acc, 4);
  if ((lane & 7) == 0) rden[(size_t)row * 8 + h] = 1.0f / acc;
}

extern "C" void kernel_launch(void* const* d_in, const int* in_sizes, int n_in,
                              void* d_out, int out_size, void* d_ws, size_t ws_size,
                              hipStream_t stream) {
  (void)in_sizes; (void)n_in; (void)out_size; (void)ws_size;
  const float* x     = (const float*)d_in[0];
  const float* ln1_g = (const float*)d_in[1];
  const float* ln1_b = (const float*)d_in[2];
  const float* Wq    = (const float*)d_in[3];
  const float* bq    = (const float*)d_in[4];
  const float* Wk    = (const float*)d_in[5];
  const float* bk    = (const float*)d_in[6];
  const float* Wv    = (const float*)d_in[7];
  const float* bv    = (const float*)d_in[8];
  const float* Wo    = (const float*)d_in[9];
  const float* bo    = (const float*)d_in[10];
  const float* omega = (const float*)d_in[11];
  const float* g1_Wr = (const float*)d_in[12];
  const float* g1_Ur = (const float*)d_in[13];
  const float* g1_Wz = (const float*)d_in[14];
  const float* g1_Uz = (const float*)d_in[15];
  const float* g1_Wg = (const float*)d_in[16];
  const float* g1_Ug = (const float*)d_in[17];
  const float* g1_bg = (const float*)d_in[18];
  const float* ln2_g = (const float*)d_in[19];
  const float* ln2_b = (const float*)d_in[20];
  const float* W1    = (const float*)d_in[21];
  const float* b1    = (const float*)d_in[22];
  const float* W2    = (const float*)d_in[23];
  const float* b2    = (const float*)d_in[24];
  const float* g2_Wr = (const float*)d_in[25];
  const float* g2_Ur = (const float*)d_in[26];
  const float* g2_Wz = (const float*)d_in[27];
  const float* g2_Uz = (const float*)d_in[28];
  const float* g2_Wg = (const float*)d_in[29];
  const float* g2_Ug = (const float*)d_in[30];
  const float* g2_bg = (const float*)d_in[31];

  const size_t SZ  = (size_t)BN * 256;
  float* T1     = (float*)d_ws;                       // 67 MB
  float* T2     = T1 + SZ;                            // 67 MB
  float* wphi   = T2 + SZ;                            // 512 KB
  float* kvpart = wphi + 131072;                      // 8.65 MB
  float* kvfin  = kvpart + (size_t)64 * KSPLIT * 2112;
  float* kvbd   = kvfin + 135168;                     // 4 MB
  float* auxb   = kvbd + 1048576;                     // 2 MB (sq -> rden)
  unsigned short* db = (unsigned short*)d_out;        // bf16 scratch views
  unsigned short* t2b = (unsigned short*)T2;

  dim3 blk(256);
  dim3 g256(2, BN / 128);
  dim3 g512(4, BN / 128);
  const float SQCOEF = 0.0883883476483184f;  // 0.5 * 32^-0.5

  wphi_kernel<<<512, blk, 0, stream>>>(omega, wphi);
  // ---- attention ----
  ln_kernel<<<BN / 4, blk, 0, stream>>>(x, ln1_g, ln1_b, T1);                      // T1 = h
  gemm_kernel<0,0,0,0,0><<<g256, blk, 0, stream>>>(T1,256, nullptr,0, Wk,nullptr,256, bk, nullptr,nullptr, T2,256, 256);    // T2 = K
  sqh_kernel<<<BN / 4, blk, 0, stream>>>(T2, auxb, SQCOEF);
  gemm_kernel<5,0,0,1,0><<<g512, blk, 0, stream>>>(T2,256, nullptr,0, wphi,nullptr,512, nullptr, auxb,nullptr, db,512, 256); // pk bf16 (d_out)
  gemm_kernel<0,0,0,1,0><<<g256, blk, 0, stream>>>(T1,256, nullptr,0, Wv,nullptr,256, bv, nullptr,nullptr, t2b,256, 256);   // V bf16 (T2)
  kv_partial2_kernel<<<dim3(64, KSPLIT), blk, 0, stream>>>(db, t2b, kvpart);
  kv_reduce_kernel<<<64, blk, 0, stream>>>(kvpart, kvfin);
  kvbd_kernel<<<4096, blk, 0, stream>>>(kvfin, kvbd);
  gemm_kernel<0,0,0,0,0><<<g256, blk, 0, stream>>>(T1,256, nullptr,0, Wq,nullptr,256, bq, nullptr,nullptr, T2,256, 256);    // T2 = Q
  sqh_kernel<<<BN / 4, blk, 0, stream>>>(T2, auxb, SQCOEF);
  gemm_kernel<5,0,0,1,0><<<g512, blk, 0, stream>>>(T2,256, nullptr,0, wphi,nullptr,512, nullptr, auxb,nullptr, db,512, 256); // pq bf16 (d_out)
  den_kernel<<<BN / 4, blk, 0, stream>>>(db, kvfin, auxb);                          // auxb = 1/den
  gemm_kernel<6,1,1,0,1><<<g256, blk, 0, stream>>>(db,512, db+256,512, kvbd, kvbd+65536,256, nullptr, auxb,nullptr, T1,256, 512); // T1 = att
  gemm_kernel<0,0,0,0,0><<<g256, blk, 0, stream>>>(T1,256, nullptr,0, Wo,nullptr,256, bo, nullptr,nullptr, T2,256, 256);    // T2 = y1
  // ---- gate 1 (y=T2, x=input) ----
  gemm_kernel<3,0,0,1,0><<<g256, blk, 0, stream>>>(T2,256, x,256, g1_Wr,g1_Ur,256, nullptr, x,nullptr, db,256, 512);        // rx1 bf16
  gemm_kernel<2,0,0,1,0><<<g256, blk, 0, stream>>>(T2,256, x,256, g1_Wz,g1_Uz,256, g1_bg, nullptr,nullptr, db+SZ,256, 512); // z1 bf16
  gemm_kernel<4,0,1,0,0><<<g256, blk, 0, stream>>>(T2,256, db,256, g1_Wg,g1_Ug,256, nullptr, x, db+SZ, T1,256, 512);        // T1 = out1
  // ---- MLP ----
  ln_kernel<<<BN / 4, blk, 0, stream>>>(T1, ln2_g, ln2_b, T2);                      // T2 = ln2
  gemm_kernel<1,0,0,1,0><<<g512, blk, 0, stream>>>(T2,256, nullptr,0, W1,nullptr,512, b1, nullptr,nullptr, db,512, 256);    // hid bf16
  gemm_kernel<1,1,1,0,0><<<g256, blk, 0, stream>>>(db,512, db+256,512, W2, W2+65536,256, b2, nullptr,nullptr, T2,256, 512); // T2 = y2
  // ---- gate 2 (y=T2, x=out1=T1) ----
  gemm_kernel<3,0,0,1,0><<<g256, blk, 0, stream>>>(T2,256, T1,256, g2_Wr,g2_Ur,256, nullptr, T1,nullptr, db,256, 512);      // rx2 bf16
  gemm_kernel<2,0,0,1,0><<<g256, blk, 0, stream>>>(T2,256, T1,256, g2_Wz,g2_Uz,256, g2_bg, nullptr,nullptr, db+SZ,256, 512);// z2 bf16
  gemm_kernel<4,0,1,0,0><<<g256, blk, 0, stream>>>(T2,256, db,256, g2_Wg,g2_Ug,256, nullptr, T1, db+SZ, T1,256, 512);       // T1 = final
  hipMemcpyAsync(d_out, T1, SZ * sizeof(float), hipMemcpyDeviceToDevice, stream);
}

// Round 4
// 959.834 us; speedup vs baseline: 2.1745x; 1.3605x over previous
//
#include <hip/hip_runtime.h>

#define B_ 8
#define N_ 8192
#define H_ 8
#define KSPLIT 16
#define BN 65536  // B_*N_

typedef float f32x4 __attribute__((ext_vector_type(4)));
typedef __bf16 bf16x8 __attribute__((ext_vector_type(8)));
typedef unsigned short u16;

__device__ __forceinline__ u16 f2b(float f) {
  union { float f; unsigned u; } v; v.f = f;
  return (u16)((v.u + 0x7fffu + ((v.u >> 16) & 1u)) >> 16);
}
__device__ __forceinline__ float b2f(u16 u) {
  union { unsigned u; float f; } v; v.u = ((unsigned)u) << 16;
  return v.f;
}

// async global->LDS 16B (CK-style addrspace casts via integer round-trip)
__device__ __forceinline__ void gload16(const void* g, const void* lds) {
  __builtin_amdgcn_global_load_lds(
      (const __attribute__((address_space(1))) unsigned int*)(unsigned long long)g,
      (__attribute__((address_space(3))) unsigned int*)(unsigned long long)lds,
      16, 0, 0);
}

// ---------------------------------------------------------------------------
// bf16 MFMA GEMM, 128x128 tile, BK=32, global_load_lds staging, XOR swizzle.
// A: bf16 [M][K] (A1 k<256, A2 k>=256; A2F32 -> A2 is f32, manual staging).
// BT: bf16 [Nc][K] pre-transposed weight panel.
// MODE 0: bf16 C = acc + bias[col]
// MODE 1: bf16 C = relu(acc + bias[col])
// MODE 4: C = (1-z)*X + z*tanh(acc); z=auxZ bf16, X per XBF; CF32 -> f32 C
// MODE 5: bf16 C = exp(acc - auxS[row*8+col/64]) * 0.125
// MODE 6: bf16 C = acc * auxS[row*8+col/32]
// MODE 7: QKV: bf16 {Cv,Cv2,Cv3}[row][col&255] = acc + bias[col(768)]
// MODE 8: rz: col<256 -> Cv = bf16 sigmoid(acc)*X ; else Cv2 = bf16 sigmoid(acc-bias)
// BSEL: BT += (by>>6)*131072 (per-batch kv panel)
// ---------------------------------------------------------------------------
template <int MODE, int A2F32, int XBF, int CF32, int BSEL>
__global__ __launch_bounds__(256) void gemm2(
    const u16* __restrict__ A1, int lda1, const void* __restrict__ A2v, int lda2,
    const u16* __restrict__ BT, int ldb,
    const float* __restrict__ bias, const void* __restrict__ auxX,
    const u16* __restrict__ auxZ, const float* __restrict__ auxS,
    void* __restrict__ Cv, void* __restrict__ Cv2, void* __restrict__ Cv3,
    int ldc, int K) {
  __shared__ __align__(16) u16 As[128 * 32];
  __shared__ __align__(16) u16 Bs[128 * 32];
  const int t = threadIdx.x, lane = t & 63, w = t >> 6;
  // XCD-aware bijective remap (all grids are multiples of 8 blocks)
  const int nwg = gridDim.x * gridDim.y;
  const int flat = blockIdx.x + gridDim.x * blockIdx.y;
  const int wg = (flat & 7) * (nwg >> 3) + (flat >> 3);
  const int bx = wg % gridDim.x, by = wg / gridDim.x;
  const int rowBase = by * 128, colBase = bx * 128;
  if (BSEL) BT += (size_t)(by >> 6) * 131072;  // 256*512 per batch

  const int srow = lane >> 2;    // 0..15
  const int sslot = lane & 3;    // 16B granule

  f32x4 acc[4][4];
#pragma unroll
  for (int m = 0; m < 4; ++m)
#pragma unroll
    for (int n = 0; n < 4; ++n) acc[m][n] = 0.f;

  for (int k0 = 0; k0 < K; k0 += 32) {
    if (k0) __syncthreads();
    // ---- stage A (128x32 bf16) ----
    if (!A2F32 || k0 < 256) {
      const u16* Ap; int la, ka;
      if (k0 < 256) { Ap = A1; la = lda1; ka = k0; }
      else          { Ap = (const u16*)A2v; la = lda2; ka = k0 - 256; }
#pragma unroll
      for (int j = 0; j < 2; ++j) {
        int row = (w * 2 + j) * 16 + srow;
        int ks = (sslot ^ ((row & 6) >> 1)) * 8;
        gload16(&Ap[(size_t)(rowBase + row) * la + ka + ks],
                &As[(size_t)(w * 2 + j) * 512 + lane * 8]);
      }
    } else {  // f32 A2 (gate1 rz: x) manual cvt staging with matching swizzle
      const float* Ap = (const float*)A2v; int ka = k0 - 256;
#pragma unroll
      for (int i = 0; i < 4; ++i) {
        int slot = t + 256 * i;
        int row = slot >> 3, kq = slot & 7;
        float4 v = *(const float4*)&Ap[(size_t)(rowBase + row) * lda2 + ka + kq * 4];
        ushort4 p; p.x = f2b(v.x); p.y = f2b(v.y); p.z = f2b(v.z); p.w = f2b(v.w);
        int g = (kq >> 1) ^ ((row & 6) >> 1);
        *(ushort4*)&As[row * 32 + g * 8 + (kq & 1) * 4] = p;
      }
    }
    // ---- stage B^T (128x32 bf16) ----
#pragma unroll
    for (int j = 0; j < 2; ++j) {
      int col = (w * 2 + j) * 16 + srow;
      int ks = (sslot ^ ((col & 6) >> 1)) * 8;
      gload16(&BT[(size_t)(colBase + col) * ldb + k0 + ks],
              &Bs[(size_t)(w * 2 + j) * 512 + lane * 8]);
    }
    __syncthreads();
    // ---- fragments + MFMA ----
    const int lr = lane & 15, kg = lane >> 4;
    const int wrow = (w >> 1) * 64, wcol = (w & 1) * 64;
    bf16x8 af[4], bf[4];
#pragma unroll
    for (int m = 0; m < 4; ++m) {
      int row = wrow + m * 16 + lr;
      af[m] = *(const bf16x8*)&As[row * 32 + (kg ^ ((row & 6) >> 1)) * 8];
    }
#pragma unroll
    for (int n = 0; n < 4; ++n) {
      int col = wcol + n * 16 + lr;
      bf[n] = *(const bf16x8*)&Bs[col * 32 + (kg ^ ((col & 6) >> 1)) * 8];
    }
#pragma unroll
    for (int m = 0; m < 4; ++m)
#pragma unroll
      for (int n = 0; n < 4; ++n)
        acc[m][n] = __builtin_amdgcn_mfma_f32_16x16x32_bf16(af[m], bf[n], acc[m][n], 0, 0, 0);
  }
  // ---- epilogue: row = wrow+m*16+kg*4+i, col = wcol+n*16+lr ----
  const int lr = lane & 15, kg = lane >> 4;
  const int wrow = (w >> 1) * 64, wcol = (w & 1) * 64;
#pragma unroll
  for (int n = 0; n < 4; ++n) {
    int col = colBase + wcol + n * 16 + lr;
#pragma unroll
    for (int m = 0; m < 4; ++m) {
#pragma unroll
      for (int i = 0; i < 4; ++i) {
        int row = rowBase + wrow + m * 16 + kg * 4 + i;
        float v = acc[m][n][i];
        if (MODE == 0) {
          ((u16*)Cv)[(size_t)row * ldc + col] = f2b(v + bias[col]);
        } else if (MODE == 1) {
          ((u16*)Cv)[(size_t)row * ldc + col] = f2b(fmaxf(v + bias[col], 0.f));
        } else if (MODE == 4) {
          float z = b2f(auxZ[(size_t)row * 256 + col]);
          float xv = XBF ? b2f(((const u16*)auxX)[(size_t)row * 256 + col])
                         : ((const float*)auxX)[(size_t)row * 256 + col];
          float o = (1.f - z) * xv + z * tanhf(v);
          if (CF32) ((float*)Cv)[(size_t)row * 256 + col] = o;
          else      ((u16*)Cv)[(size_t)row * 256 + col] = f2b(o);
        } else if (MODE == 5) {
          float o = __expf(v - auxS[(size_t)row * 8 + (col >> 6)]) * 0.125f;
          ((u16*)Cv)[(size_t)row * (size_t)ldc + col] = f2b(o);
        } else if (MODE == 6) {
          ((u16*)Cv)[(size_t)row * 256 + col] = f2b(v * auxS[(size_t)row * 8 + (col >> 5)]);
        } else if (MODE == 7) {
          float o = v + bias[col];
          u16* Cp; int c2;
          if (colBase < 256)      { Cp = (u16*)Cv;  c2 = col; }
          else if (colBase < 512) { Cp = (u16*)Cv2; c2 = col - 256; }
          else                    { Cp = (u16*)Cv3; c2 = col - 512; }
          Cp[(size_t)row * 256 + c2] = f2b(o);
        } else if (MODE == 8) {
          if (colBase < 256) {
            float xv = XBF ? b2f(((const u16*)auxX)[(size_t)row * 256 + col])
                           : ((const float*)auxX)[(size_t)row * 256 + col];
            ((u16*)Cv)[(size_t)row * 256 + col] = f2b((1.f / (1.f + __expf(-v))) * xv);
          } else {
            float o = 1.f / (1.f + __expf(-(v - bias[col - 256])));
            ((u16*)Cv2)[(size_t)row * 256 + col - 256] = f2b(o);
          }
        }
      }
    }
  }
}

// ---------------------------------------------------------------------------
// batched weight transpose f32 [rows][cols] -> bf16 [cols][ldd]
struct TJob { const float* s; u16* d; int lds, ldd, rows, cols; };
struct TJobs { TJob j[18]; };
__global__ __launch_bounds__(256) void wt_kernel(TJobs J) {
  TJob jb = J.j[blockIdx.y];
  int ntc = jb.cols >> 6;
  int tile = blockIdx.x;
  if (tile >= (jb.rows >> 6) * ntc) return;
  int tr = (tile / ntc) << 6, tc = (tile % ntc) << 6;
  __shared__ float sm[64][68];
  int t = threadIdx.x;
#pragma unroll
  for (int i = 0; i < 4; ++i) {
    int idx = t + 256 * i;
    int r = idx >> 4, c = (idx & 15) * 4;
    float4 v = *(const float4*)&jb.s[(size_t)(tr + r) * jb.lds + tc + c];
    sm[r][c] = v.x; sm[r][c + 1] = v.y; sm[r][c + 2] = v.z; sm[r][c + 3] = v.w;
  }
  __syncthreads();
#pragma unroll
  for (int i = 0; i < 4; ++i) {
    int idx = t + 256 * i;
    int c = idx >> 4, r = (idx & 15) * 4;
    ushort4 p; p.x = f2b(sm[r][c]); p.y = f2b(sm[r + 1][c]);
    p.z = f2b(sm[r + 2][c]); p.w = f2b(sm[r + 3][c]);
    *(ushort4*)&jb.d[(size_t)(tc + c) * jb.ldd + tr + r] = p;
  }
}

__global__ __launch_bounds__(256) void wphiT_kernel(const float* __restrict__ omega,
                                                    u16* __restrict__ w) {
  int idx = blockIdx.x * 256 + threadIdx.x;  // 512*256
  int c = idx >> 8, k = idx & 255;
  float v = 0.f;
  if ((k >> 5) == (c >> 6)) v = omega[(k & 31) * 64 + (c & 63)] * 0.4204482076268573f;
  w[idx] = f2b(v);
}

__global__ __launch_bounds__(256) void bias_kernel(const float* bk, const float* bv,
                                                   const float* bq, float* dst) {
  int t = threadIdx.x;
  dst[t] = bk[t]; dst[256 + t] = bv[t]; dst[512 + t] = bq[t];
}

__global__ __launch_bounds__(256) void kvbdT_kernel(const float* __restrict__ kvfin,
                                                    u16* __restrict__ kb) {
  int idx = blockIdx.x * 256 + threadIdx.x;  // 8*256*512
  int b = idx >> 17, rem = idx & 131071;
  int c = rem >> 9, k = rem & 511;
  float v = 0.f;
  if ((k >> 6) == (c >> 5))
    v = kvfin[(size_t)(b * 8 + (k >> 6)) * 2112 + (k & 63) * 32 + (c & 31)];
  kb[idx] = f2b(v);
}

// ---------------------------------------------------------------------------
template <int XBF>
__global__ __launch_bounds__(256) void ln_kernel2(const void* __restrict__ xv,
                                                  const float* __restrict__ g,
                                                  const float* __restrict__ b,
                                                  u16* __restrict__ out) {
  const int row = blockIdx.x * 4 + (threadIdx.x >> 6);
  const int lane = threadIdx.x & 63;
  float v[4];
  if (XBF) {
    uint2 u = *(const uint2*)&((const u16*)xv)[(size_t)row * 256 + lane * 4];
    v[0] = b2f((u16)(u.x & 0xffff)); v[1] = b2f((u16)(u.x >> 16));
    v[2] = b2f((u16)(u.y & 0xffff)); v[3] = b2f((u16)(u.y >> 16));
  } else {
    float4 f = *(const float4*)&((const float*)xv)[(size_t)row * 256 + lane * 4];
    v[0] = f.x; v[1] = f.y; v[2] = f.z; v[3] = f.w;
  }
  float s = v[0] + v[1] + v[2] + v[3];
  float s2 = v[0] * v[0] + v[1] * v[1] + v[2] * v[2] + v[3] * v[3];
#pragma unroll
  for (int off = 1; off < 64; off <<= 1) {
    s += __shfl_xor(s, off);
    s2 += __shfl_xor(s2, off);
  }
  const float mu = s * (1.f / 256.f);
  const float var = s2 * (1.f / 256.f) - mu * mu;
  const float rs = rsqrtf(var + 1e-3f);
  const float4 gv = *(const float4*)&g[lane * 4];
  const float4 bv = *(const float4*)&b[lane * 4];
  ushort4 o;
  o.x = f2b(gv.x * (v[0] - mu) * rs + bv.x);
  o.y = f2b(gv.y * (v[1] - mu) * rs + bv.y);
  o.z = f2b(gv.z * (v[2] - mu) * rs + bv.z);
  o.w = f2b(gv.w * (v[3] - mu) * rs + bv.w);
  *(ushort4*)&out[(size_t)row * 256 + lane * 4] = o;
}

// per-head 0.5*scale^2*sum(x^2) from bf16 input
__global__ __launch_bounds__(256) void sqh_kernel2(const u16* __restrict__ X,
                                                   float* __restrict__ sq) {
  const int row = blockIdx.x * 4 + (threadIdx.x >> 6);
  const int lane = threadIdx.x & 63;
  uint2 u = *(const uint2*)&X[(size_t)row * 256 + lane * 4];
  float a = b2f((u16)(u.x & 0xffff)), bb = b2f((u16)(u.x >> 16));
  float c = b2f((u16)(u.y & 0xffff)), d = b2f((u16)(u.y >> 16));
  float s = a * a + bb * bb + c * c + d * d;
  s += __shfl_xor(s, 1); s += __shfl_xor(s, 2); s += __shfl_xor(s, 4);
  if ((lane & 7) == 0) sq[(size_t)row * 8 + (lane >> 3)] = 0.0883883476483184f * s;
}

// ---------------------------------------------------------------------------
__global__ __launch_bounds__(256) void kv_partial2_kernel(const u16* __restrict__ pk,
                                                          const u16* __restrict__ v,
                                                          float* __restrict__ part) {
  __shared__ __align__(16) u16 pks[128 * 64];
  __shared__ __align__(16) u16 vs[128 * 32];
  const int bh = blockIdx.x, split = blockIdx.y;
  const int b = bh >> 3, h = bh & 7;
  const int t = threadIdx.x;
  const int d = t & 31, mg = t >> 5;
  float acc[8], sacc[8];
#pragma unroll
  for (int j = 0; j < 8; ++j) { acc[j] = 0.f; sacc[j] = 0.f; }
  const size_t rbase = (size_t)b * N_ + (size_t)split * (N_ / KSPLIT);
  for (int tile = 0; tile < (N_ / KSPLIT) / 128; ++tile) {
    __syncthreads();
#pragma unroll
    for (int i = 0; i < 4; ++i) {
      int slot = t + 256 * i;
      int tok = slot >> 3, mo = slot & 7;
      uint4 q = *(const uint4*)&pk[(rbase + tile * 128 + tok) * 512 + h * 64 + mo * 8];
      *(uint4*)&pks[tok * 64 + mo * 8] = q;
    }
#pragma unroll
    for (int i = 0; i < 2; ++i) {
      int slot = t + 256 * i;
      int tok = slot >> 2, qo = slot & 3;
      uint4 q = *(const uint4*)&v[(rbase + tile * 128 + tok) * 256 + h * 32 + qo * 8];
      *(uint4*)&vs[tok * 32 + qo * 8] = q;
    }
    __syncthreads();
#pragma unroll 2
    for (int tok = 0; tok < 128; ++tok) {
      float vval = b2f(vs[tok * 32 + d]);
      uint4 pv = *(const uint4*)&pks[tok * 64 + mg * 8];
      const unsigned uu[4] = {pv.x, pv.y, pv.z, pv.w};
#pragma unroll
      for (int j = 0; j < 4; ++j) {
        union { unsigned u; float f; } lo, hi;
        lo.u = uu[j] << 16; hi.u = uu[j] & 0xffff0000u;
        acc[2 * j]     = __fmaf_rn(lo.f, vval, acc[2 * j]);
        acc[2 * j + 1] = __fmaf_rn(hi.f, vval, acc[2 * j + 1]);
        sacc[2 * j] += lo.f; sacc[2 * j + 1] += hi.f;
      }
    }
  }
  float* dst = part + (size_t)(bh * KSPLIT + split) * 2112;
#pragma unroll
  for (int mm = 0; mm < 8; ++mm) dst[(mg * 8 + mm) * 32 + d] = acc[mm];
  if (d == 0) {
#pragma unroll
    for (int mm = 0; mm < 8; ++mm) dst[2048 + mg * 8 + mm] = sacc[mm];
  }
}

__global__ __launch_bounds__(256) void kv_reduce_kernel(const float* __restrict__ part,
                                                        float* __restrict__ fin) {
  const int bh = blockIdx.x, t = threadIdx.x;
  for (int idx = t; idx < 2112; idx += 256) {
    float s = 0.f;
#pragma unroll
    for (int sp = 0; sp < KSPLIT; ++sp) s += part[(size_t)(bh * KSPLIT + sp) * 2112 + idx];
    fin[(size_t)bh * 2112 + idx] = s;
  }
}

__global__ __launch_bounds__(256) void den_kernel(const u16* __restrict__ pq,
                                                  const float* __restrict__ kvfin,
                                                  float* __restrict__ rden) {
  const int row = blockIdx.x * 4 + (threadIdx.x >> 6);
  const int lane = threadIdx.x & 63;
  const int h = lane >> 3, m0 = (lane & 7) * 8;
  const int b = row >> 13;
  const float* s = &kvfin[(size_t)(b * 8 + h) * 2112 + 2048 + m0];
  uint4 pv = *(const uint4*)&pq[(size_t)row * 512 + h * 64 + m0];
  const unsigned uu[4] = {pv.x, pv.y, pv.z, pv.w};
  float acc = 0.f;
#pragma unroll
  for (int j = 0; j < 4; ++j) {
    union { unsigned u; float f; } lo, hi;
    lo.u = uu[j] << 16; hi.u = uu[j] & 0xffff0000u;
    acc = __fmaf_rn(lo.f, s[2 * j], acc);
    acc = __fmaf_rn(hi.f, s[2 * j + 1], acc);
  }
  acc += __shfl_xor(acc, 1); acc += __shfl_xor(acc, 2); acc += __shfl_xor(acc, 4);
  if ((lane & 7) == 0) rden[(size_t)row * 8 + h] = 1.0f / acc;
}

// ---------------------------------------------------------------------------
extern "C" void kernel_launch(void* const* d_in, const int* in_sizes, int n_in,
                              void* d_out, int out_size, void* d_ws, size_t ws_size,
                              hipStream_t stream) {
  (void)in_sizes; (void)n_in; (void)out_size; (void)ws_size;
  const float* x     = (const float*)d_in[0];
  const float* ln1_g = (const float*)d_in[1];
  const float* ln1_b = (const float*)d_in[2];
  const float* Wq    = (const float*)d_in[3];
  const float* bq    = (const float*)d_in[4];
  const float* Wk    = (const float*)d_in[5];
  const float* bk    = (const float*)d_in[6];
  const float* Wv    = (const float*)d_in[7];
  const float* bv    = (const float*)d_in[8];
  const float* Wo    = (const float*)d_in[9];
  const float* bo    = (const float*)d_in[10];
  const float* omega = (const float*)d_in[11];
  const float* g1_Wr = (const float*)d_in[12];
  const float* g1_Ur = (const float*)d_in[13];
  const float* g1_Wz = (const float*)d_in[14];
  const float* g1_Uz = (const float*)d_in[15];
  const float* g1_Wg = (const float*)d_in[16];
  const float* g1_Ug = (const float*)d_in[17];
  const float* g1_bg = (const float*)d_in[18];
  const float* ln2_g = (const float*)d_in[19];
  const float* ln2_b = (const float*)d_in[20];
  const float* W1    = (const float*)d_in[21];
  const float* b1    = (const float*)d_in[22];
  const float* W2    = (const float*)d_in[23];
  const float* b2    = (const float*)d_in[24];
  const float* g2_Wr = (const float*)d_in[25];
  const float* g2_Ur = (const float*)d_in[26];
  const float* g2_Wz = (const float*)d_in[27];
  const float* g2_Uz = (const float*)d_in[28];
  const float* g2_Wg = (const float*)d_in[29];
  const float* g2_Ug = (const float*)d_in[30];
  const float* g2_bg = (const float*)d_in[31];

  const size_t SZB = (size_t)BN * 256;
  u16* S0 = (u16*)d_ws;            // h -> ln2h -> z2
  u16* S1 = S0 + SZB;              // K -> rx1 -> y2
  u16* S2 = S1 + SZB;              // V -> z1 -> rx2
  u16* S3 = S2 + SZB;              // Q -> att -> out1
  u16* qkvT  = S3 + SZB;           // [768][256]
  u16* wphiT = qkvT + 768 * 256;   // [512][256]
  u16* woT   = wphiT + 512 * 256;  // [256][256]
  u16* g1rzT = woT + 65536;        // [512][512]
  u16* g1hpT = g1rzT + 262144;     // [256][512]
  u16* w1T   = g1hpT + 131072;     // [512][256]
  u16* w2T   = w1T + 131072;       // [256][512]
  u16* g2rzT = w2T + 131072;       // [512][512]
  u16* g2hpT = g2rzT + 262144;     // [256][512]
  u16* kvbdT = g2hpT + 131072;     // [8][256][512]
  float* bias768 = (float*)(kvbdT + 1048576);
  float* kvpart  = bias768 + 768;                   // 64*16*2112
  float* kvfin   = kvpart + (size_t)64 * KSPLIT * 2112;
  float* sq      = kvfin + 64 * 2112;               // BN*8 (reused as rden)
  u16* db = (u16*)d_out;
  float* outf = (float*)d_out;

  dim3 blk(256);
  dim3 g2x(2, BN / 128), g4x(4, BN / 128), g6x(6, BN / 128);

  // ---- weight prep ----
  TJobs J;
  auto job = [](const float* s, u16* d, int lds, int ldd, int r, int c) {
    TJob t; t.s = s; t.d = d; t.lds = lds; t.ldd = ldd; t.rows = r; t.cols = c; return t;
  };
  J.j[0]  = job(Wk, qkvT, 256, 256, 256, 256);
  J.j[1]  = job(Wv, qkvT + 256 * 256, 256, 256, 256, 256);
  J.j[2]  = job(Wq, qkvT + 512 * 256, 256, 256, 256, 256);
  J.j[3]  = job(Wo, woT, 256, 256, 256, 256);
  J.j[4]  = job(g1_Wr, g1rzT, 256, 512, 256, 256);
  J.j[5]  = job(g1_Ur, g1rzT + 256, 256, 512, 256, 256);
  J.j[6]  = job(g1_Wz, g1rzT + 256 * 512, 256, 512, 256, 256);
  J.j[7]  = job(g1_Uz, g1rzT + 256 * 512 + 256, 256, 512, 256, 256);
  J.j[8]  = job(g1_Wg, g1hpT, 256, 512, 256, 256);
  J.j[9]  = job(g1_Ug, g1hpT + 256, 256, 512, 256, 256);
  J.j[10] = job(W1, w1T, 512, 256, 256, 512);
  J.j[11] = job(W2, w2T, 256, 512, 512, 256);
  J.j[12] = job(g2_Wr, g2rzT, 256, 512, 256, 256);
  J.j[13] = job(g2_Ur, g2rzT + 256, 256, 512, 256, 256);
  J.j[14] = job(g2_Wz, g2rzT + 256 * 512, 256, 512, 256, 256);
  J.j[15] = job(g2_Uz, g2rzT + 256 * 512 + 256, 256, 512, 256, 256);
  J.j[16] = job(g2_Wg, g2hpT, 256, 512, 256, 256);
  J.j[17] = job(g2_Ug, g2hpT + 256, 256, 512, 256, 256);
  wt_kernel<<<dim3(32, 18), blk, 0, stream>>>(J);
  wphiT_kernel<<<512, blk, 0, stream>>>(omega, wphiT);
  bias_kernel<<<1, blk, 0, stream>>>(bk, bv, bq, bias768);

  // ---- attention ----
  ln_kernel2<0><<<BN / 4, blk, 0, stream>>>(x, ln1_g, ln1_b, S0);  // h
  gemm2<7,0,0,0,0><<<g6x, blk, 0, stream>>>(S0, 256, S0, 256, qkvT, 256,
      bias768, nullptr, nullptr, nullptr, S1, S2, S3, 256, 256);   // K,V,Q
  sqh_kernel2<<<BN / 4, blk, 0, stream>>>(S1, sq);
  gemm2<5,0,0,0,0><<<g4x, blk, 0, stream>>>(S1, 256, S1, 256, wphiT, 256,
      nullptr, nullptr, nullptr, sq, db, nullptr, nullptr, 512, 256);  // pk -> d_out
  kv_partial2_kernel<<<dim3(64, KSPLIT), blk, 0, stream>>>(db, S2, kvpart);
  kv_reduce_kernel<<<64, blk, 0, stream>>>(kvpart, kvfin);
  kvbdT_kernel<<<4096, blk, 0, stream>>>(kvfin, kvbdT);
  sqh_kernel2<<<BN / 4, blk, 0, stream>>>(S3, sq);
  gemm2<5,0,0,0,0><<<g4x, blk, 0, stream>>>(S3, 256, S3, 256, wphiT, 256,
      nullptr, nullptr, nullptr, sq, db, nullptr, nullptr, 512, 256);  // pq -> d_out
  den_kernel<<<BN / 4, blk, 0, stream>>>(db, kvfin, sq);               // sq = 1/den
  gemm2<6,0,0,0,1><<<g2x, blk, 0, stream>>>(db, 512, db + 256, 512, kvbdT, 512,
      nullptr, nullptr, nullptr, sq, S3, nullptr, nullptr, 256, 512);  // att -> S3
  gemm2<0,0,0,0,0><<<g2x, blk, 0, stream>>>(S3, 256, S3, 256, woT, 256,
      bo, nullptr, nullptr, nullptr, db, nullptr, nullptr, 256, 256);  // y1 -> d_out(lo)
  // ---- gate 1 (y=y1(db), x=input f32) ----
  gemm2<8,1,0,0,0><<<g4x, blk, 0, stream>>>(db, 256, x, 256, g1rzT, 512,
      g1_bg, x, nullptr, nullptr, S1, S2, nullptr, 256, 512);          // rx1->S1, z1->S2
  gemm2<4,0,0,0,0><<<g2x, blk, 0, stream>>>(db, 256, S1, 256, g1hpT, 512,
      nullptr, x, S2, nullptr, S3, nullptr, nullptr, 256, 512);        // out1 -> S3 (bf16)
  // ---- MLP ----
  ln_kernel2<1><<<BN / 4, blk, 0, stream>>>(S3, ln2_g, ln2_b, S0);     // ln2h -> S0
  gemm2<1,0,0,0,0><<<g4x, blk, 0, stream>>>(S0, 256, S0, 256, w1T, 256,
      b1, nullptr, nullptr, nullptr, db, nullptr, nullptr, 512, 256);  // hid -> d_out
  gemm2<1,0,0,0,0><<<g2x, blk, 0, stream>>>(db, 512, db + 256, 512, w2T, 512,
      b2, nullptr, nullptr, nullptr, S1, nullptr, nullptr, 256, 512);  // y2 -> S1
  // ---- gate 2 (y=y2(S1), x=out1(S3) bf16) ----
  gemm2<8,0,1,0,0><<<g4x, blk, 0, stream>>>(S1, 256, S3, 256, g2rzT, 512,
      g2_bg, S3, nullptr, nullptr, S2, S0, nullptr, 256, 512);         // rx2->S2, z2->S0
  gemm2<4,0,1,1,0><<<g2x, blk, 0, stream>>>(S1, 256, S2, 256, g2hpT, 512,
      nullptr, S3, S0, nullptr, outf, nullptr, nullptr, 256, 512);     // final -> d_out f32
}

// Round 5
// 747.310 us; speedup vs baseline: 2.7929x; 1.2844x over previous
//
#include <hip/hip_runtime.h>

#define B_ 8
#define N_ 8192
#define H_ 8
#define KSPLIT 16
#define BN 65536  // B_*N_

typedef float f32x4 __attribute__((ext_vector_type(4)));
typedef __bf16 bf16x8 __attribute__((ext_vector_type(8)));
typedef unsigned short u16;

__device__ __forceinline__ u16 f2b(float f) {
  union { float f; unsigned u; } v; v.f = f;
  return (u16)((v.u + 0x7fffu + ((v.u >> 16) & 1u)) >> 16);
}
__device__ __forceinline__ float b2f(u16 u) {
  union { unsigned u; float f; } v; v.u = ((unsigned)u) << 16;
  return v.f;
}

// async global->LDS 16B
__device__ __forceinline__ void gload16(const void* g, const void* lds) {
  __builtin_amdgcn_global_load_lds(
      (const __attribute__((address_space(1))) unsigned int*)(unsigned long long)g,
      (__attribute__((address_space(3))) unsigned int*)(unsigned long long)lds,
      16, 0, 0);
}

__device__ __forceinline__ void ld16f(const float* p, float* f) {
#pragma unroll
  for (int j = 0; j < 4; ++j) {
    float4 q = *(const float4*)(p + j * 4);
    f[j * 4 + 0] = q.x; f[j * 4 + 1] = q.y; f[j * 4 + 2] = q.z; f[j * 4 + 3] = q.w;
  }
}
__device__ __forceinline__ void ld16b(const u16* p, float* f) {
  uint4 a = *(const uint4*)p, b = *(const uint4*)(p + 8);
  const unsigned uu[8] = {a.x, a.y, a.z, a.w, b.x, b.y, b.z, b.w};
#pragma unroll
  for (int j = 0; j < 8; ++j) {
    f[2 * j]     = b2f((u16)(uu[j] & 0xffff));
    f[2 * j + 1] = b2f((u16)(uu[j] >> 16));
  }
}
__device__ __forceinline__ void st16b(u16* p, const float* f) {
  u16 o[16];
#pragma unroll
  for (int j = 0; j < 16; ++j) o[j] = f2b(f[j]);
  *(uint4*)p = *(const uint4*)o;
  *(uint4*)(p + 8) = *(const uint4*)(o + 8);
}
__device__ __forceinline__ void st16f(float* p, const float* f) {
#pragma unroll
  for (int j = 0; j < 4; ++j) {
    float4 q; q.x = f[j * 4]; q.y = f[j * 4 + 1]; q.z = f[j * 4 + 2]; q.w = f[j * 4 + 3];
    *(float4*)(p + j * 4) = q;
  }
}

// ---------------------------------------------------------------------------
// bf16 MFMA GEMM, 128x128 tile, BK=32, dbuf LDS + 1-deep prefetch,
// global_load_lds staging, XOR swizzle, coalesced LDS-repacked epilogue.
// MODE 0: bf16 C = acc + bias[col]
// MODE 1: bf16 C = relu(acc + bias[col])
// MODE 4: C = (1-z)*X + z*tanh(acc); z=auxZ bf16, X per XBF; CF32 -> f32 C
// MODE 5: bf16 C = exp(acc - auxS[row*8+col/64]) * 0.125
// MODE 6: bf16 C = acc * auxS[row*8+col/32]
// MODE 7: QKV split: {Cv,Cv2,Cv3}[row][col-seg] = acc + bias[col(768)]
// MODE 8: rz: col<256 -> Cv = sigmoid(acc)*X ; else Cv2 = sigmoid(acc-bias)
// ---------------------------------------------------------------------------
template <int MODE, int A2F32, int XBF, int CF32, int BSEL>
__global__ __launch_bounds__(256) void gemm2(
    const u16* __restrict__ A1, int lda1, const void* __restrict__ A2v, int lda2,
    const u16* __restrict__ BT, int ldb,
    const float* __restrict__ bias, const void* __restrict__ auxX,
    const u16* __restrict__ auxZ, const float* __restrict__ auxS,
    void* __restrict__ Cv, void* __restrict__ Cv2, void* __restrict__ Cv3,
    int ldc, int K) {
  __shared__ __align__(16) u16 As[2][128 * 32];
  __shared__ __align__(16) u16 Bs[2][128 * 32];
  const int t = threadIdx.x, lane = t & 63, w = t >> 6;
  // XCD-aware bijective remap (all grids are multiples of 8 blocks)
  const int nwg = gridDim.x * gridDim.y;
  const int flat = blockIdx.x + gridDim.x * blockIdx.y;
  const int wg = (flat & 7) * (nwg >> 3) + (flat >> 3);
  const int bx = wg % gridDim.x, by = wg / gridDim.x;
  const int rowBase = by * 128, colBase = bx * 128;
  const u16* BTb = BSEL ? BT + (size_t)(by >> 6) * 131072 : BT;

  const int srow = lane >> 2, sslot = lane & 3;
  const int lr = lane & 15, kg = lane >> 4;
  const int wrow = (w >> 1) * 64, wcol = (w & 1) * 64;

  f32x4 acc[4][4];
#pragma unroll
  for (int m = 0; m < 4; ++m)
#pragma unroll
    for (int n = 0; n < 4; ++n) acc[m][n] = 0.f;

  const int nt = K >> 5;
  auto stage = [&](int buf, int k0) {
    if (!A2F32 || k0 < 256) {
      const u16* Ap; int la, ka;
      if (k0 < 256) { Ap = A1; la = lda1; ka = k0; }
      else          { Ap = (const u16*)A2v; la = lda2; ka = k0 - 256; }
#pragma unroll
      for (int j = 0; j < 2; ++j) {
        int row = (w * 2 + j) * 16 + srow;
        int ks = (sslot ^ ((row & 6) >> 1)) * 8;
        gload16(&Ap[(size_t)(rowBase + row) * la + ka + ks],
                &As[buf][(w * 2 + j) * 512 + lane * 8]);
      }
    } else {  // f32 A2 manual cvt staging with matching swizzle
      const float* Ap = (const float*)A2v; int ka = k0 - 256;
#pragma unroll
      for (int i = 0; i < 4; ++i) {
        int slot = t + 256 * i;
        int row = slot >> 3, kq = slot & 7;
        float4 v = *(const float4*)&Ap[(size_t)(rowBase + row) * lda2 + ka + kq * 4];
        ushort4 p; p.x = f2b(v.x); p.y = f2b(v.y); p.z = f2b(v.z); p.w = f2b(v.w);
        int g = (kq >> 1) ^ ((row & 6) >> 1);
        *(ushort4*)&As[buf][row * 32 + g * 8 + (kq & 1) * 4] = p;
      }
    }
#pragma unroll
    for (int j = 0; j < 2; ++j) {
      int col = (w * 2 + j) * 16 + srow;
      int ks = (sslot ^ ((col & 6) >> 1)) * 8;
      gload16(&BTb[(size_t)(colBase + col) * ldb + k0 + ks],
              &Bs[buf][(w * 2 + j) * 512 + lane * 8]);
    }
  };

  stage(0, 0);
  __syncthreads();
  int cur = 0;
  for (int tt = 0; tt < nt; ++tt) {
    if (tt + 1 < nt) stage(cur ^ 1, (tt + 1) * 32);  // prefetch while computing
    bf16x8 af[4], bf[4];
#pragma unroll
    for (int m = 0; m < 4; ++m) {
      int row = wrow + m * 16 + lr;
      af[m] = *(const bf16x8*)&As[cur][row * 32 + (kg ^ ((row & 6) >> 1)) * 8];
    }
#pragma unroll
    for (int n = 0; n < 4; ++n) {
      int col = wcol + n * 16 + lr;
      bf[n] = *(const bf16x8*)&Bs[cur][col * 32 + (kg ^ ((col & 6) >> 1)) * 8];
    }
#pragma unroll
    for (int m = 0; m < 4; ++m)
#pragma unroll
      for (int n = 0; n < 4; ++n)
        acc[m][n] = __builtin_amdgcn_mfma_f32_16x16x32_bf16(af[m], bf[n], acc[m][n], 0, 0, 0);
    __syncthreads();  // drains prefetch (vmcnt0) + protects buf swap
    cur ^= 1;
  }

  // ---- epilogue: repack through LDS, 16B-coalesced stores + aux loads ----
  float* scr = (float*)&As[0][0];  // 32 rows x 132 f32 = 16.9 KB (fits 16 KB x2)
#pragma unroll
  for (int m = 0; m < 4; ++m) {
    if (m) __syncthreads();
#pragma unroll
    for (int n = 0; n < 4; ++n)
#pragma unroll
      for (int i = 0; i < 4; ++i)
        scr[((w >> 1) * 16 + kg * 4 + i) * 132 + wcol + n * 16 + lr] = acc[m][n][i];
    __syncthreads();
    const int sr = t >> 3, cs = (t & 7) * 16;
    const int grow = rowBase + (sr >> 4) * 64 + m * 16 + (sr & 15);
    const int gcol = colBase + cs;
    float vv[16];
#pragma unroll
    for (int j = 0; j < 4; ++j) {
      float4 q = *(const float4*)&scr[sr * 132 + cs + j * 4];
      vv[j * 4] = q.x; vv[j * 4 + 1] = q.y; vv[j * 4 + 2] = q.z; vv[j * 4 + 3] = q.w;
    }
    if (MODE == 0 || MODE == 1) {
      float bb[16]; ld16f(&bias[gcol], bb);
#pragma unroll
      for (int j = 0; j < 16; ++j) {
        vv[j] += bb[j];
        if (MODE == 1) vv[j] = fmaxf(vv[j], 0.f);
      }
      st16b(&((u16*)Cv)[(size_t)grow * ldc + gcol], vv);
    } else if (MODE == 5) {
      float s = auxS[(size_t)grow * 8 + (gcol >> 6)];
#pragma unroll
      for (int j = 0; j < 16; ++j) vv[j] = __expf(vv[j] - s) * 0.125f;
      st16b(&((u16*)Cv)[(size_t)grow * ldc + gcol], vv);
    } else if (MODE == 6) {
      float s = auxS[(size_t)grow * 8 + (gcol >> 5)];
#pragma unroll
      for (int j = 0; j < 16; ++j) vv[j] *= s;
      st16b(&((u16*)Cv)[(size_t)grow * ldc + gcol], vv);
    } else if (MODE == 7) {
      float bb[16]; ld16f(&bias[gcol], bb);
#pragma unroll
      for (int j = 0; j < 16; ++j) vv[j] += bb[j];
      u16* Cp; int c2;
      if (colBase < 256)      { Cp = (u16*)Cv;  c2 = gcol; }
      else if (colBase < 512) { Cp = (u16*)Cv2; c2 = gcol - 256; }
      else                    { Cp = (u16*)Cv3; c2 = gcol - 512; }
      st16b(&Cp[(size_t)grow * ldc + c2], vv);
    } else if (MODE == 8) {
      if (colBase < 256) {
        float xv[16];
        if (XBF) ld16b(&((const u16*)auxX)[(size_t)grow * 256 + gcol], xv);
        else     ld16f(&((const float*)auxX)[(size_t)grow * 256 + gcol], xv);
#pragma unroll
        for (int j = 0; j < 16; ++j) vv[j] = (1.f / (1.f + __expf(-vv[j]))) * xv[j];
        st16b(&((u16*)Cv)[(size_t)grow * ldc + gcol], vv);
      } else {
        float bb[16]; ld16f(&bias[gcol - 256], bb);
#pragma unroll
        for (int j = 0; j < 16; ++j) vv[j] = 1.f / (1.f + __expf(-(vv[j] - bb[j])));
        st16b(&((u16*)Cv2)[(size_t)grow * ldc + gcol - 256], vv);
      }
    } else if (MODE == 4) {
      float zz[16], xv[16];
      ld16b(&auxZ[(size_t)grow * 256 + gcol], zz);
      if (XBF) ld16b(&((const u16*)auxX)[(size_t)grow * 256 + gcol], xv);
      else     ld16f(&((const float*)auxX)[(size_t)grow * 256 + gcol], xv);
#pragma unroll
      for (int j = 0; j < 16; ++j)
        vv[j] = (1.f - zz[j]) * xv[j] + zz[j] * tanhf(vv[j]);
      if (CF32) st16f(&((float*)Cv)[(size_t)grow * ldc + gcol], vv);
      else      st16b(&((u16*)Cv)[(size_t)grow * ldc + gcol], vv);
    }
  }
}

// ---------------------------------------------------------------------------
// batched weight transpose f32 [rows][cols] -> bf16 [cols][ldd]
struct TJob { const float* s; u16* d; int lds, ldd, rows, cols; };
struct TJobs { TJob j[18]; };
__global__ __launch_bounds__(256) void wt_kernel(TJobs J) {
  TJob jb = J.j[blockIdx.y];
  int ntc = jb.cols >> 6;
  int tile = blockIdx.x;
  if (tile >= (jb.rows >> 6) * ntc) return;
  int tr = (tile / ntc) << 6, tc = (tile % ntc) << 6;
  __shared__ float sm[64][68];
  int t = threadIdx.x;
#pragma unroll
  for (int i = 0; i < 4; ++i) {
    int idx = t + 256 * i;
    int r = idx >> 4, c = (idx & 15) * 4;
    float4 v = *(const float4*)&jb.s[(size_t)(tr + r) * jb.lds + tc + c];
    sm[r][c] = v.x; sm[r][c + 1] = v.y; sm[r][c + 2] = v.z; sm[r][c + 3] = v.w;
  }
  __syncthreads();
#pragma unroll
  for (int i = 0; i < 4; ++i) {
    int idx = t + 256 * i;
    int c = idx >> 4, r = (idx & 15) * 4;
    ushort4 p; p.x = f2b(sm[r][c]); p.y = f2b(sm[r + 1][c]);
    p.z = f2b(sm[r + 2][c]); p.w = f2b(sm[r + 3][c]);
    *(ushort4*)&jb.d[(size_t)(tc + c) * jb.ldd + tr + r] = p;
  }
}

__global__ __launch_bounds__(256) void wphiT_kernel(const float* __restrict__ omega,
                                                    u16* __restrict__ w) {
  int idx = blockIdx.x * 256 + threadIdx.x;  // 512*256
  int c = idx >> 8, k = idx & 255;
  float v = 0.f;
  if ((k >> 5) == (c >> 6)) v = omega[(k & 31) * 64 + (c & 63)] * 0.4204482076268573f;
  w[idx] = f2b(v);
}

__global__ __launch_bounds__(256) void bias_kernel(const float* bk, const float* bv,
                                                   const float* bq, float* dst) {
  int t = threadIdx.x;
  dst[t] = bk[t]; dst[256 + t] = bv[t]; dst[512 + t] = bq[t];
}

__global__ __launch_bounds__(256) void kvbdT_kernel(const float* __restrict__ kvfin,
                                                    u16* __restrict__ kb) {
  int idx = blockIdx.x * 256 + threadIdx.x;  // 8*256*512
  int b = idx >> 17, rem = idx & 131071;
  int c = rem >> 9, k = rem & 511;
  float v = 0.f;
  if ((k >> 6) == (c >> 5))
    v = kvfin[(size_t)(b * 8 + (k >> 6)) * 2112 + (k & 63) * 32 + (c & 31)];
  kb[idx] = f2b(v);
}

// ---------------------------------------------------------------------------
template <int XBF>
__global__ __launch_bounds__(256) void ln_kernel2(const void* __restrict__ xv,
                                                  const float* __restrict__ g,
                                                  const float* __restrict__ b,
                                                  u16* __restrict__ out) {
  const int row = blockIdx.x * 4 + (threadIdx.x >> 6);
  const int lane = threadIdx.x & 63;
  float v[4];
  if (XBF) {
    uint2 u = *(const uint2*)&((const u16*)xv)[(size_t)row * 256 + lane * 4];
    v[0] = b2f((u16)(u.x & 0xffff)); v[1] = b2f((u16)(u.x >> 16));
    v[2] = b2f((u16)(u.y & 0xffff)); v[3] = b2f((u16)(u.y >> 16));
  } else {
    float4 f = *(const float4*)&((const float*)xv)[(size_t)row * 256 + lane * 4];
    v[0] = f.x; v[1] = f.y; v[2] = f.z; v[3] = f.w;
  }
  float s = v[0] + v[1] + v[2] + v[3];
  float s2 = v[0] * v[0] + v[1] * v[1] + v[2] * v[2] + v[3] * v[3];
#pragma unroll
  for (int off = 1; off < 64; off <<= 1) {
    s += __shfl_xor(s, off);
    s2 += __shfl_xor(s2, off);
  }
  const float mu = s * (1.f / 256.f);
  const float var = s2 * (1.f / 256.f) - mu * mu;
  const float rs = rsqrtf(var + 1e-3f);
  const float4 gv = *(const float4*)&g[lane * 4];
  const float4 bv = *(const float4*)&b[lane * 4];
  ushort4 o;
  o.x = f2b(gv.x * (v[0] - mu) * rs + bv.x);
  o.y = f2b(gv.y * (v[1] - mu) * rs + bv.y);
  o.z = f2b(gv.z * (v[2] - mu) * rs + bv.z);
  o.w = f2b(gv.w * (v[3] - mu) * rs + bv.w);
  *(ushort4*)&out[(size_t)row * 256 + lane * 4] = o;
}

__global__ __launch_bounds__(256) void sqh_kernel2(const u16* __restrict__ X,
                                                   float* __restrict__ sq) {
  const int row = blockIdx.x * 4 + (threadIdx.x >> 6);
  const int lane = threadIdx.x & 63;
  uint2 u = *(const uint2*)&X[(size_t)row * 256 + lane * 4];
  float a = b2f((u16)(u.x & 0xffff)), bb = b2f((u16)(u.x >> 16));
  float c = b2f((u16)(u.y & 0xffff)), d = b2f((u16)(u.y >> 16));
  float s = a * a + bb * bb + c * c + d * d;
  s += __shfl_xor(s, 1); s += __shfl_xor(s, 2); s += __shfl_xor(s, 4);
  if ((lane & 7) == 0) sq[(size_t)row * 8 + (lane >> 3)] = 0.0883883476483184f * s;
}

// ---------------------------------------------------------------------------
__global__ __launch_bounds__(256) void kv_partial2_kernel(const u16* __restrict__ pk,
                                                          const u16* __restrict__ v,
                                                          float* __restrict__ part) {
  __shared__ __align__(16) u16 pks[128 * 64];
  __shared__ __align__(16) u16 vs[128 * 32];
  const int bh = blockIdx.x, split = blockIdx.y;
  const int b = bh >> 3, h = bh & 7;
  const int t = threadIdx.x;
  const int d = t & 31, mg = t >> 5;
  float acc[8], sacc[8];
#pragma unroll
  for (int j = 0; j < 8; ++j) { acc[j] = 0.f; sacc[j] = 0.f; }
  const size_t rbase = (size_t)b * N_ + (size_t)split * (N_ / KSPLIT);
  for (int tile = 0; tile < (N_ / KSPLIT) / 128; ++tile) {
    __syncthreads();
#pragma unroll
    for (int i = 0; i < 4; ++i) {
      int slot = t + 256 * i;
      int tok = slot >> 3, mo = slot & 7;
      uint4 q = *(const uint4*)&pk[(rbase + tile * 128 + tok) * 512 + h * 64 + mo * 8];
      *(uint4*)&pks[tok * 64 + mo * 8] = q;
    }
#pragma unroll
    for (int i = 0; i < 2; ++i) {
      int slot = t + 256 * i;
      int tok = slot >> 2, qo = slot & 3;
      uint4 q = *(const uint4*)&v[(rbase + tile * 128 + tok) * 256 + h * 32 + qo * 8];
      *(uint4*)&vs[tok * 32 + qo * 8] = q;
    }
    __syncthreads();
#pragma unroll 2
    for (int tok = 0; tok < 128; ++tok) {
      float vval = b2f(vs[tok * 32 + d]);
      uint4 pv = *(const uint4*)&pks[tok * 64 + mg * 8];
      const unsigned uu[4] = {pv.x, pv.y, pv.z, pv.w};
#pragma unroll
      for (int j = 0; j < 4; ++j) {
        union { unsigned u; float f; } lo, hi;
        lo.u = uu[j] << 16; hi.u = uu[j] & 0xffff0000u;
        acc[2 * j]     = __fmaf_rn(lo.f, vval, acc[2 * j]);
        acc[2 * j + 1] = __fmaf_rn(hi.f, vval, acc[2 * j + 1]);
        sacc[2 * j] += lo.f; sacc[2 * j + 1] += hi.f;
      }
    }
  }
  float* dst = part + (size_t)(bh * KSPLIT + split) * 2112;
#pragma unroll
  for (int mm = 0; mm < 8; ++mm) dst[(mg * 8 + mm) * 32 + d] = acc[mm];
  if (d == 0) {
#pragma unroll
    for (int mm = 0; mm < 8; ++mm) dst[2048 + mg * 8 + mm] = sacc[mm];
  }
}

__global__ __launch_bounds__(256) void kv_reduce_kernel(const float* __restrict__ part,
                                                        float* __restrict__ fin) {
  const int bh = blockIdx.x, t = threadIdx.x;
  for (int idx = t; idx < 2112; idx += 256) {
    float s = 0.f;
#pragma unroll
    for (int sp = 0; sp < KSPLIT; ++sp) s += part[(size_t)(bh * KSPLIT + sp) * 2112 + idx];
    fin[(size_t)bh * 2112 + idx] = s;
  }
}

__global__ __launch_bounds__(256) void den_kernel(const u16* __restrict__ pq,
                                                  const float* __restrict__ kvfin,
                                                  float* __restrict__ rden) {
  const int row = blockIdx.x * 4 + (threadIdx.x >> 6);
  const int lane = threadIdx.x & 63;
  const int h = lane >> 3, m0 = (lane & 7) * 8;
  const int b = row >> 13;
  const float* s = &kvfin[(size_t)(b * 8 + h) * 2112 + 2048 + m0];
  uint4 pv = *(const uint4*)&pq[(size_t)row * 512 + h * 64 + m0];
  const unsigned uu[4] = {pv.x, pv.y, pv.z, pv.w};
  float acc = 0.f;
#pragma unroll
  for (int j = 0; j < 4; ++j) {
    union { unsigned u; float f; } lo, hi;
    lo.u = uu[j] << 16; hi.u = uu[j] & 0xffff0000u;
    acc = __fmaf_rn(lo.f, s[2 * j], acc);
    acc = __fmaf_rn(hi.f, s[2 * j + 1], acc);
  }
  acc += __shfl_xor(acc, 1); acc += __shfl_xor(acc, 2); acc += __shfl_xor(acc, 4);
  if ((lane & 7) == 0) rden[(size_t)row * 8 + h] = 1.0f / acc;
}

// ---------------------------------------------------------------------------
extern "C" void kernel_launch(void* const* d_in, const int* in_sizes, int n_in,
                              void* d_out, int out_size, void* d_ws, size_t ws_size,
                              hipStream_t stream) {
  (void)in_sizes; (void)n_in; (void)out_size; (void)ws_size;
  const float* x     = (const float*)d_in[0];
  const float* ln1_g = (const float*)d_in[1];
  const float* ln1_b = (const float*)d_in[2];
  const float* Wq    = (const float*)d_in[3];
  const float* bq    = (const float*)d_in[4];
  const float* Wk    = (const float*)d_in[5];
  const float* bk    = (const float*)d_in[6];
  const float* Wv    = (const float*)d_in[7];
  const float* bv    = (const float*)d_in[8];
  const float* Wo    = (const float*)d_in[9];
  const float* bo    = (const float*)d_in[10];
  const float* omega = (const float*)d_in[11];
  const float* g1_Wr = (const float*)d_in[12];
  const float* g1_Ur = (const float*)d_in[13];
  const float* g1_Wz = (const float*)d_in[14];
  const float* g1_Uz = (const float*)d_in[15];
  const float* g1_Wg = (const float*)d_in[16];
  const float* g1_Ug = (const float*)d_in[17];
  const float* g1_bg = (const float*)d_in[18];
  const float* ln2_g = (const float*)d_in[19];
  const float* ln2_b = (const float*)d_in[20];
  const float* W1    = (const float*)d_in[21];
  const float* b1    = (const float*)d_in[22];
  const float* W2    = (const float*)d_in[23];
  const float* b2    = (const float*)d_in[24];
  const float* g2_Wr = (const float*)d_in[25];
  const float* g2_Ur = (const float*)d_in[26];
  const float* g2_Wz = (const float*)d_in[27];
  const float* g2_Uz = (const float*)d_in[28];
  const float* g2_Wg = (const float*)d_in[29];
  const float* g2_Ug = (const float*)d_in[30];
  const float* g2_bg = (const float*)d_in[31];

  const size_t SZB = (size_t)BN * 256;
  u16* S0 = (u16*)d_ws;            // h -> ln2h -> z2
  u16* S1 = S0 + SZB;              // K -> rx1 -> y2
  u16* S2 = S1 + SZB;              // V -> z1 -> rx2
  u16* S3 = S2 + SZB;              // Q -> att -> out1
  u16* qkvT  = S3 + SZB;           // [768][256]
  u16* wphiT = qkvT + 768 * 256;   // [512][256]
  u16* woT   = wphiT + 512 * 256;  // [256][256]
  u16* g1rzT = woT + 65536;        // [512][512]
  u16* g1hpT = g1rzT + 262144;     // [256][512]
  u16* w1T   = g1hpT + 131072;     // [512][256]
  u16* w2T   = w1T + 131072;       // [256][512]
  u16* g2rzT = w2T + 131072;       // [512][512]
  u16* g2hpT = g2rzT + 262144;     // [256][512]
  u16* kvbdT = g2hpT + 131072;     // [8][256][512]
  float* bias768 = (float*)(kvbdT + 1048576);
  float* kvpart  = bias768 + 768;                   // 64*16*2112
  float* kvfin   = kvpart + (size_t)64 * KSPLIT * 2112;
  float* sq      = kvfin + 64 * 2112;               // BN*8 (reused as rden)
  u16* db = (u16*)d_out;
  float* outf = (float*)d_out;

  dim3 blk(256);
  dim3 g2x(2, BN / 128), g4x(4, BN / 128), g6x(6, BN / 128);

  // ---- weight prep ----
  TJobs J;
  auto job = [](const float* s, u16* d, int lds, int ldd, int r, int c) {
    TJob t; t.s = s; t.d = d; t.lds = lds; t.ldd = ldd; t.rows = r; t.cols = c; return t;
  };
  J.j[0]  = job(Wk, qkvT, 256, 256, 256, 256);
  J.j[1]  = job(Wv, qkvT + 256 * 256, 256, 256, 256, 256);
  J.j[2]  = job(Wq, qkvT + 512 * 256, 256, 256, 256, 256);
  J.j[3]  = job(Wo, woT, 256, 256, 256, 256);
  J.j[4]  = job(g1_Wr, g1rzT, 256, 512, 256, 256);
  J.j[5]  = job(g1_Ur, g1rzT + 256, 256, 512, 256, 256);
  J.j[6]  = job(g1_Wz, g1rzT + 256 * 512, 256, 512, 256, 256);
  J.j[7]  = job(g1_Uz, g1rzT + 256 * 512 + 256, 256, 512, 256, 256);
  J.j[8]  = job(g1_Wg, g1hpT, 256, 512, 256, 256);
  J.j[9]  = job(g1_Ug, g1hpT + 256, 256, 512, 256, 256);
  J.j[10] = job(W1, w1T, 512, 256, 256, 512);
  J.j[11] = job(W2, w2T, 256, 512, 512, 256);
  J.j[12] = job(g2_Wr, g2rzT, 256, 512, 256, 256);
  J.j[13] = job(g2_Ur, g2rzT + 256, 256, 512, 256, 256);
  J.j[14] = job(g2_Wz, g2rzT + 256 * 512, 256, 512, 256, 256);
  J.j[15] = job(g2_Uz, g2rzT + 256 * 512 + 256, 256, 512, 256, 256);
  J.j[16] = job(g2_Wg, g2hpT, 256, 512, 256, 256);
  J.j[17] = job(g2_Ug, g2hpT + 256, 256, 512, 256, 256);
  wt_kernel<<<dim3(32, 18), blk, 0, stream>>>(J);
  wphiT_kernel<<<512, blk, 0, stream>>>(omega, wphiT);
  bias_kernel<<<1, blk, 0, stream>>>(bk, bv, bq, bias768);

  // ---- attention ----
  ln_kernel2<0><<<BN / 4, blk, 0, stream>>>(x, ln1_g, ln1_b, S0);  // h
  gemm2<7,0,0,0,0><<<g6x, blk, 0, stream>>>(S0, 256, S0, 256, qkvT, 256,
      bias768, nullptr, nullptr, nullptr, S1, S2, S3, 256, 256);   // K,V,Q
  sqh_kernel2<<<BN / 4, blk, 0, stream>>>(S1, sq);
  gemm2<5,0,0,0,0><<<g4x, blk, 0, stream>>>(S1, 256, S1, 256, wphiT, 256,
      nullptr, nullptr, nullptr, sq, db, nullptr, nullptr, 512, 256);  // pk -> d_out
  kv_partial2_kernel<<<dim3(64, KSPLIT), blk, 0, stream>>>(db, S2, kvpart);
  kv_reduce_kernel<<<64, blk, 0, stream>>>(kvpart, kvfin);
  kvbdT_kernel<<<4096, blk, 0, stream>>>(kvfin, kvbdT);
  sqh_kernel2<<<BN / 4, blk, 0, stream>>>(S3, sq);
  gemm2<5,0,0,0,0><<<g4x, blk, 0, stream>>>(S3, 256, S3, 256, wphiT, 256,
      nullptr, nullptr, nullptr, sq, db, nullptr, nullptr, 512, 256);  // pq -> d_out
  den_kernel<<<BN / 4, blk, 0, stream>>>(db, kvfin, sq);               // sq = 1/den
  gemm2<6,0,0,0,1><<<g2x, blk, 0, stream>>>(db, 512, db + 256, 512, kvbdT, 512,
      nullptr, nullptr, nullptr, sq, S3, nullptr, nullptr, 256, 512);  // att -> S3
  gemm2<0,0,0,0,0><<<g2x, blk, 0, stream>>>(S3, 256, S3, 256, woT, 256,
      bo, nullptr, nullptr, nullptr, db, nullptr, nullptr, 256, 256);  // y1 -> d_out(lo)
  // ---- gate 1 (y=y1(db), x=input f32) ----
  gemm2<8,1,0,0,0><<<g4x, blk, 0, stream>>>(db, 256, x, 256, g1rzT, 512,
      g1_bg, x, nullptr, nullptr, S1, S2, nullptr, 256, 512);          // rx1->S1, z1->S2
  gemm2<4,0,0,0,0><<<g2x, blk, 0, stream>>>(db, 256, S1, 256, g1hpT, 512,
      nullptr, x, S2, nullptr, S3, nullptr, nullptr, 256, 512);        // out1 -> S3 (bf16)
  // ---- MLP ----
  ln_kernel2<1><<<BN / 4, blk, 0, stream>>>(S3, ln2_g, ln2_b, S0);     // ln2h -> S0
  gemm2<1,0,0,0,0><<<g4x, blk, 0, stream>>>(S0, 256, S0, 256, w1T, 256,
      b1, nullptr, nullptr, nullptr, db, nullptr, nullptr, 512, 256);  // hid -> d_out
  gemm2<1,0,0,0,0><<<g2x, blk, 0, stream>>>(db, 512, db + 256, 512, w2T, 512,
      b2, nullptr, nullptr, nullptr, S1, nullptr, nullptr, 256, 512);  // y2 -> S1
  // ---- gate 2 (y=y2(S1), x=out1(S3) bf16) ----
  gemm2<8,0,1,0,0><<<g4x, blk, 0, stream>>>(S1, 256, S3, 256, g2rzT, 512,
      g2_bg, S3, nullptr, nullptr, S2, S0, nullptr, 256, 512);         // rx2->S2, z2->S0
  gemm2<4,0,1,1,0><<<g2x, blk, 0, stream>>>(S1, 256, S2, 256, g2hpT, 512,
      nullptr, S3, S0, nullptr, outf, nullptr, nullptr, 256, 512);     // final -> d_out f32
}